// Round 7
// baseline (682.450 us; speedup 1.0000x reference)
//
#include <hip/hip_runtime.h>
#include <math.h>

// ---------------- problem constants ----------------
constexpr int kB = 4, kW = 2000, kI = 64, kS = 64, kT = 24, kU = 32, kUS = 2;
constexpr int kPER = kW + kI + kS + kU + 1;   // 2161 nodes per graph
constexpr int kN   = kB * kPER;               // 8644 nodes total
constexpr int kTxtPer  = kW + kS + kU + 1;    // 2097 text rows per graph
constexpr int kTxtRows = kB * kTxtPer;        // 8388 text rows
constexpr int kEmb = 300;
constexpr int kEmbPad = 320;
constexpr int kHid = 1024;
constexpr int kOut = 512;
constexpr int kCap = 256;                     // max gathered rows for sparse gat2
constexpr int kN4Pad = 34624;                 // kN*4 rounded up to 256B/4

typedef __attribute__((ext_vector_type(8))) short bf16x8;
typedef __attribute__((ext_vector_type(4))) float f32x4;

__device__ __forceinline__ unsigned short f2bf(float f) {
  union { float f; unsigned int u; } x; x.f = f;
  unsigned int r = x.u + 0x7FFF + ((x.u >> 16) & 1);
  return (unsigned short)(r >> 16);
}
__device__ __forceinline__ float bf2f(unsigned short u) {
  union { unsigned int u; float f; } x; x.u = ((unsigned int)u) << 16;
  return x.f;
}

// ---------------- feature construction (fp32) ----------------

__global__ void k_sent(const int* __restrict__ sents, const float* __restrict__ smask,
                       const float* __restrict__ wemb, float* __restrict__ sent) {
  int bs = blockIdx.x;
  __shared__ int idx[kT];
  __shared__ float mk[kT];
  __shared__ float s_cnt;
  int t = threadIdx.x;
  if (t < kT) { idx[t] = sents[bs * kT + t]; mk[t] = smask[bs * kT + t]; }
  __syncthreads();
  if (t == 0) {
    float c = 0.f;
    for (int i = 0; i < kT; ++i) c += mk[i];
    s_cnt = (c == 0.f) ? 1.f : c;
  }
  __syncthreads();
  for (int d = t; d < kEmb; d += blockDim.x) {
    float acc = 0.f;
    for (int i = 0; i < kT; ++i) acc += wemb[idx[i] * kEmb + d] * mk[i];
    sent[bs * kEmb + d] = acc / s_cnt;
  }
}

__global__ void k_utt(const int* __restrict__ utts, const float* __restrict__ umask,
                      const float* __restrict__ sent, float* __restrict__ utt) {
  int bu = blockIdx.x;
  int b = bu / kU;
  __shared__ int idx[kUS];
  __shared__ float mk[kUS];
  __shared__ float s_cnt;
  int t = threadIdx.x;
  if (t < kUS) { idx[t] = utts[bu * kUS + t]; mk[t] = umask[bu * kUS + t]; }
  __syncthreads();
  if (t == 0) {
    float c = 0.f;
    for (int i = 0; i < kUS; ++i) c += mk[i];
    s_cnt = (c == 0.f) ? 1.f : c;
  }
  __syncthreads();
  for (int d = t; d < kEmb; d += blockDim.x) {
    float acc = 0.f;
    for (int i = 0; i < kUS; ++i) acc += sent[(b * kS + idx[i]) * kEmb + d] * mk[i];
    utt[bu * kEmb + d] = acc / s_cnt;
  }
}

__global__ void k_sess(const float* __restrict__ utt, float* __restrict__ sess) {
  int b = blockIdx.x;
  for (int d = threadIdx.x; d < kEmb; d += blockDim.x) {
    float acc = 0.f;
    for (int u = 0; u < kU; ++u) acc += utt[(b * kU + u) * kEmb + d];
    sess[b * kEmb + d] = acc * (1.f / kU);
  }
}

__global__ void k_txtgather(const int* __restrict__ aw, const float* __restrict__ wemb,
                            const float* __restrict__ sent, const float* __restrict__ utt,
                            const float* __restrict__ sess, unsigned short* __restrict__ txt) {
  int r = blockIdx.x;
  int g = r / kTxtPer, j = r - g * kTxtPer;
  const float* src;
  if (j < kW)                 src = wemb + (size_t)aw[g * kW + j] * kEmb;
  else if (j < kW + kS)       src = sent + (size_t)(g * kS + (j - kW)) * kEmb;
  else if (j < kW + kS + kU)  src = utt  + (size_t)(g * kU + (j - kW - kS)) * kEmb;
  else                        src = sess + (size_t)g * kEmb;
  for (int d = threadIdx.x; d < kEmbPad; d += blockDim.x)
    txt[(size_t)r * kEmbPad + d] = (d < kEmb) ? f2bf(src[d]) : (unsigned short)0;
}

__global__ void k_rowmap(int* __restrict__ rt, int* __restrict__ ri) {
  int i = blockIdx.x * blockDim.x + threadIdx.x;
  if (i < kTxtRows) {
    int g = i / kTxtPer, j = i - g * kTxtPer;
    int base = g * kPER;
    int node;
    if (j < kW)                 node = base + j;
    else if (j < kW + kS)       node = base + kW + kI + (j - kW);
    else if (j < kW + kS + kU)  node = base + kW + kI + kS + (j - kW - kS);
    else                        node = base + kW + kI + kS + kU;
    rt[i] = node;
  }
  if (i < kB * kI) {
    int g = i >> 6;
    ri[i] = g * kPER + kW + (i & 63);
  }
}

// ---------------- fused prep: 5 weight transposes + image f2bf ----------------
__global__ void k_prep(const float* __restrict__ tx_w, unsigned short* __restrict__ o_tx,
                       const float* __restrict__ im_w, unsigned short* __restrict__ o_im,
                       const float* __restrict__ g0_w, unsigned short* __restrict__ o_g0,
                       const float* __restrict__ g1_w, unsigned short* __restrict__ o_g1,
                       const float* __restrict__ g2_w, unsigned short* __restrict__ o_g2,
                       const float* __restrict__ img, unsigned short* __restrict__ o_img) {
  int b = blockIdx.x;
  int tx = threadIdx.x, ty = threadIdx.y;
  const float* in; unsigned short* out; int K, N, Kpad, nbx;
  if (b < 320)               { in = tx_w; out = o_tx; K = kEmb; N = kHid; Kpad = kEmbPad; nbx = 32; }
  else if ((b -= 320) < 2048){ in = im_w; out = o_im; K = 2048; N = kHid; Kpad = 2048; nbx = 32; }
  else if ((b -= 2048) < 1024){ in = g0_w; out = o_g0; K = kHid; N = kHid; Kpad = kHid; nbx = 32; }
  else if ((b -= 1024) < 1024){ in = g1_w; out = o_g1; K = kHid; N = kHid; Kpad = kHid; nbx = 32; }
  else if ((b -= 1024) < 512) { in = g2_w; out = o_g2; K = kHid; N = kOut; Kpad = kHid; nbx = 16; }
  else {
    int i = (b - 512) * 1024 + (ty * 32 + tx) * 4;
    float4 v = *(const float4*)(img + i);
    ushort4 o; o.x = f2bf(v.x); o.y = f2bf(v.y); o.z = f2bf(v.z); o.w = f2bf(v.w);
    *(ushort4*)(o_img + i) = o;
    return;
  }
  int bx = b % nbx, by = b / nbx;
  __shared__ float t[32][33];
  int n = bx * 32 + tx;
#pragma unroll
  for (int j = 0; j < 4; ++j) {
    int k = by * 32 + ty + j * 8;
    t[ty + j * 8][tx] = (k < K) ? in[(size_t)k * N + n] : 0.f;
  }
  __syncthreads();
#pragma unroll
  for (int j = 0; j < 4; ++j) {
    int nn = bx * 32 + ty + j * 8;
    int kk = by * 32 + tx;
    out[(size_t)nn * Kpad + kk] = f2bf(t[tx][ty + j * 8]);
  }
}

// ---------------- bf16 MFMA GEMM, register-staged + software-pipelined ----------------
// 128x128 tile, 4 waves, XOR-swizzled LDS (chunk c of row r at c^(r&7)).
// Pipeline: ds_write(prefetched) -> barrier -> issue global loads for k+1 -> MFMA(k) -> barrier.
template <bool OBF, bool ELR>
__global__ __launch_bounds__(256) void k_mm2(const unsigned short* __restrict__ A,
                                             const unsigned short* __restrict__ Bt,
                                             const float* __restrict__ bias,
                                             const int* __restrict__ rmap,
                                             void* __restrict__ Cout,
                                             const float* __restrict__ al,
                                             const float* __restrict__ ar,
                                             float* __restrict__ el,
                                             float* __restrict__ er,
                                             int M, int K, int Nc) {
  __shared__ __align__(16) unsigned short As[128 * 64];
  __shared__ __align__(16) unsigned short Bs[128 * 64];
  int tid = threadIdx.x;
  int wid = tid >> 6, lane = tid & 63, quad = lane >> 4, l16 = lane & 15;
  int wm = wid >> 1, wn = wid & 1;
  int row0 = blockIdx.y * 128, col0 = blockIdx.x * 128;

  f32x4 acc[4][4];
  f32x4 zero4 = {0.f, 0.f, 0.f, 0.f};
#pragma unroll
  for (int i = 0; i < 4; ++i)
#pragma unroll
    for (int j = 0; j < 4; ++j) acc[i][j] = zero4;

  int ar_ = tid >> 3;       // 0..31: row within 32-row slab
  int ac = tid & 7;         // 16B chunk index 0..7

  uint4 pa[4], pb[4];
  // prefetch tile 0
#pragma unroll
  for (int i = 0; i < 4; ++i) {
    int r = ar_ + i * 32;
    int grow = row0 + r; if (grow >= M) grow = M - 1;
    pa[i] = *(const uint4*)(A + (size_t)grow * K + ac * 8);
    int nrow = col0 + r;
    pb[i] = *(const uint4*)(Bt + (size_t)nrow * K + ac * 8);
  }

  int steps = K >> 6;
  for (int s0 = 0; s0 < steps; ++s0) {
    // commit prefetched tile to LDS
#pragma unroll
    for (int i = 0; i < 4; ++i) {
      int r = ar_ + i * 32;
      int sw = ((ac ^ (r & 7)) << 3);
      *(uint4*)&As[r * 64 + sw] = pa[i];
      *(uint4*)&Bs[r * 64 + sw] = pb[i];
    }
    __syncthreads();
    // issue next tile's global loads (overlap with MFMA below)
    if (s0 + 1 < steps) {
      int k0 = (s0 + 1) << 6;
#pragma unroll
      for (int i = 0; i < 4; ++i) {
        int r = ar_ + i * 32;
        int grow = row0 + r; if (grow >= M) grow = M - 1;
        pa[i] = *(const uint4*)(A + (size_t)grow * K + k0 + ac * 8);
        int nrow = col0 + r;
        pb[i] = *(const uint4*)(Bt + (size_t)nrow * K + k0 + ac * 8);
      }
    }
    // MFMA over current LDS tile
#pragma unroll
    for (int s = 0; s < 2; ++s) {
      int cc = s * 4 + quad;
      bf16x8 aF[4], bF[4];
#pragma unroll
      for (int mi = 0; mi < 4; ++mi) {
        int r = wm * 64 + mi * 16 + l16;
        aF[mi] = *(const bf16x8*)&As[r * 64 + ((cc ^ (r & 7)) << 3)];
      }
#pragma unroll
      for (int ni = 0; ni < 4; ++ni) {
        int r = wn * 64 + ni * 16 + l16;
        bF[ni] = *(const bf16x8*)&Bs[r * 64 + ((cc ^ (r & 7)) << 3)];
      }
#pragma unroll
      for (int mi = 0; mi < 4; ++mi)
#pragma unroll
        for (int ni = 0; ni < 4; ++ni)
          acc[mi][ni] = __builtin_amdgcn_mfma_f32_16x16x32_bf16(aF[mi], bF[ni], acc[mi][ni], 0, 0, 0);
    }
    __syncthreads();
  }

  // ---- epilogue: store (C/D layout: col=lane&15, row=quad*4+reg) ----
#pragma unroll
  for (int mi = 0; mi < 4; ++mi) {
#pragma unroll
    for (int ni = 0; ni < 4; ++ni) {
      int gm0 = row0 + wm * 64 + mi * 16 + quad * 4;
      int gn  = col0 + wn * 64 + ni * 16 + l16;
      float bv = bias ? bias[gn] : 0.f;
#pragma unroll
      for (int i = 0; i < 4; ++i) {
        int r = gm0 + i;
        if (r >= M) continue;
        float v = acc[mi][ni][i] + bv;
        if (OBF) {
          int orow = rmap ? rmap[r] : r;
          ((unsigned short*)Cout)[(size_t)orow * Nc + gn] = f2bf(v);
        } else {
          ((float*)Cout)[(size_t)r * Nc + gn] = v;
        }
      }
    }
  }

  // ---- fused attention logits: this block covers head h = col0>>8 ----
  if (ELR) {
    int h = col0 >> 8;
    float alc[4], arc[4];
#pragma unroll
    for (int ni = 0; ni < 4; ++ni) {
      int c = (col0 & 255) + wn * 64 + ni * 16 + l16;
      alc[ni] = al[h * 256 + c];
      arc[ni] = ar[h * 256 + c];
    }
#pragma unroll
    for (int mi = 0; mi < 4; ++mi) {
#pragma unroll
      for (int i = 0; i < 4; ++i) {
        float se = 0.f, sr = 0.f;
#pragma unroll
        for (int ni = 0; ni < 4; ++ni) {
          float v = acc[mi][ni][i];
          se += v * alc[ni];
          sr += v * arc[ni];
        }
#pragma unroll
        for (int o = 8; o; o >>= 1) {
          se += __shfl_xor(se, o);
          sr += __shfl_xor(sr, o);
        }
        if (l16 == 0) {
          int r = row0 + wm * 64 + mi * 16 + quad * 4 + i;
          if (r < M) {
            atomicAdd(&el[r * 4 + h], se);
            atomicAdd(&er[r * 4 + h], sr);
          }
        }
      }
    }
  }
}

// ---------------- split-K bf16 MFMA GEMM (64x64 tile, optional A-row gather) ----------------
__global__ __launch_bounds__(256) void k_mm_sk(const unsigned short* __restrict__ A,
                                               const unsigned short* __restrict__ Bt,
                                               const int* __restrict__ rowlist,
                                               float* __restrict__ C,
                                               int M, int K, int Nc, int Kc) {
  __shared__ __align__(16) unsigned short As[64 * 64];
  __shared__ __align__(16) unsigned short Bs[64 * 64];
  int tid = threadIdx.x;
  int wid = tid >> 6, lane = tid & 63, quad = lane >> 4, l16 = lane & 15;
  int row0 = blockIdx.y * 64, col0 = blockIdx.x * 64;
  int k0 = blockIdx.z * Kc;
  int k1 = k0 + Kc; if (k1 > K) k1 = K;

  f32x4 acc[4];
  f32x4 zero4 = {0.f, 0.f, 0.f, 0.f};
#pragma unroll
  for (int i = 0; i < 4; ++i) acc[i] = zero4;

  int ar_ = tid >> 3;
  int ac = tid & 7;

  for (int kk = k0; kk < k1; kk += 64) {
    __syncthreads();
#pragma unroll
    for (int i = 0; i < 2; ++i) {
      int r = ar_ + i * 32;
      int sw = ((ac ^ (r & 7)) << 3);
      int grow = row0 + r;
      uint4 va = make_uint4(0u, 0u, 0u, 0u);
      if (grow < M) {
        int arow = rowlist ? rowlist[grow] : grow;
        va = *(const uint4*)(A + (size_t)arow * K + kk + ac * 8);
      }
      *(uint4*)&As[r * 64 + sw] = va;
      int nrow = col0 + r;
      uint4 vb = *(const uint4*)(Bt + (size_t)nrow * K + kk + ac * 8);
      *(uint4*)&Bs[r * 64 + sw] = vb;
    }
    __syncthreads();
#pragma unroll
    for (int s = 0; s < 2; ++s) {
      int cc = s * 4 + quad;
      bf16x8 bF;
      {
        int r = wid * 16 + l16;
        bF = *(const bf16x8*)&Bs[r * 64 + ((cc ^ (r & 7)) << 3)];
      }
#pragma unroll
      for (int mi = 0; mi < 4; ++mi) {
        int r = mi * 16 + l16;
        bf16x8 aF = *(const bf16x8*)&As[r * 64 + ((cc ^ (r & 7)) << 3)];
        acc[mi] = __builtin_amdgcn_mfma_f32_16x16x32_bf16(aF, bF, acc[mi], 0, 0, 0);
      }
    }
  }
#pragma unroll
  for (int mi = 0; mi < 4; ++mi) {
#pragma unroll
    for (int i = 0; i < 4; ++i) {
      int r = row0 + mi * 16 + quad * 4 + i;
      int c = col0 + wid * 16 + l16;
      if (r < M) atomicAdd(&C[(size_t)r * Nc + c], acc[mi][i]);
    }
  }
}

__global__ void k_sk_epi(const float* __restrict__ Cw, const float* __restrict__ bias,
                         const int* __restrict__ rmap, unsigned short* __restrict__ out,
                         int M, int Nc) {
  int i = blockIdx.x * blockDim.x + threadIdx.x;
  if (i >= M * Nc) return;
  int r = i / Nc, c = i - r * Nc;
  out[(size_t)rmap[r] * Nc + c] = f2bf(Cw[i] + bias[c]);
}

// ---------------- CSR build ----------------
__global__ void k_count(const int* __restrict__ dst, int* __restrict__ cnt, int E) {
  int e = blockIdx.x * blockDim.x + threadIdx.x;
  if (e < E) atomicAdd(&cnt[dst[e]], 1);
}

__global__ void k_scan(const int* __restrict__ deg, int* __restrict__ offs, int n) {
  __shared__ int part[1024];
  int tid = threadIdx.x;
  int per = (n + 1023) >> 10;
  int start = tid * per;
  int local = 0;
  for (int i = 0; i < per; ++i) { int idx = start + i; if (idx < n) local += deg[idx]; }
  part[tid] = local;
  __syncthreads();
  for (int off = 1; off < 1024; off <<= 1) {
    int add = (tid >= off) ? part[tid - off] : 0;
    __syncthreads();
    part[tid] += add;
    __syncthreads();
  }
  int run = (tid == 0) ? 0 : part[tid - 1];
  for (int i = 0; i < per; ++i) {
    int idx = start + i;
    if (idx < n) { offs[idx] = run; run += deg[idx]; }
  }
  if (tid == 1023) offs[n] = part[1023];
}

__global__ void k_fill(const int* __restrict__ src, const int* __restrict__ dst,
                       const int* __restrict__ offs, int* __restrict__ cur,
                       int* __restrict__ csr, int E) {
  int e = blockIdx.x * blockDim.x + threadIdx.x;
  if (e < E) {
    int d = dst[e];
    int slot = offs[d] + atomicAdd(&cur[d], 1);
    csr[slot] = src[e];
  }
}

// ---------------- per-edge softmax weights (H=4) ----------------
__global__ void k_alpha(const float* __restrict__ el, const float* __restrict__ er,
                        const int* __restrict__ offs, const int* __restrict__ csr,
                        float* __restrict__ alpha, float* __restrict__ zr) {
  int i = blockIdx.x * blockDim.x + threadIdx.x;
  if (i >= kN * 4) return;
  int v = i >> 2, h = i & 3;
  float erv = er[i];
  int e0 = offs[v], e1 = offs[v + 1];
  float m = -1e30f;
  for (int e = e0; e < e1; ++e) {
    float x = el[csr[e] * 4 + h] + erv;
    x = x > 0.f ? x : 0.2f * x;
    m = fmaxf(m, x);
  }
  float z = 0.f;
  for (int e = e0; e < e1; ++e) {
    float x = el[csr[e] * 4 + h] + erv;
    x = x > 0.f ? x : 0.2f * x;
    float w = expf(x - m);
    z += w;
    alpha[e * 4 + h] = w;
  }
  zr[i] = 1.f / z;
}

// ---------------- aggregation: bf16 gather with precomputed alpha ----------------
__global__ __launch_bounds__(256) void k_agg2(const unsigned short* __restrict__ f,
                                              const float* __restrict__ alpha,
                                              const float* __restrict__ zr,
                                              const int* __restrict__ offs,
                                              const int* __restrict__ csr,
                                              const float* __restrict__ bias,
                                              unsigned short* __restrict__ out) {
  int v = blockIdx.x;
  int tid = threadIdx.x;
  int h = tid >> 6;
  int d0 = tid * 4;
  int e0 = offs[v], e1 = offs[v + 1];
  float a0 = 0.f, a1 = 0.f, a2 = 0.f, a3 = 0.f;
  for (int e = e0; e < e1; ++e) {
    int s = csr[e];
    float w = alpha[e * 4 + h];
    ushort4 fv = *(const ushort4*)(f + (size_t)s * 1024 + d0);
    a0 += w * bf2f(fv.x);
    a1 += w * bf2f(fv.y);
    a2 += w * bf2f(fv.z);
    a3 += w * bf2f(fv.w);
  }
  float rz = zr[v * 4 + h];
  float4 bv = *(const float4*)(bias + d0);
  float o0 = a0 * rz + bv.x, o1 = a1 * rz + bv.y, o2 = a2 * rz + bv.z, o3 = a3 * rz + bv.w;
  o0 = o0 > 0.f ? o0 : expm1f(o0);
  o1 = o1 > 0.f ? o1 : expm1f(o1);
  o2 = o2 > 0.f ? o2 : expm1f(o2);
  o3 = o3 > 0.f ? o3 : expm1f(o3);
  ushort4 ov;
  ov.x = f2bf(o0); ov.y = f2bf(o1); ov.z = f2bf(o2); ov.w = f2bf(o3);
  *(ushort4*)(out + (size_t)v * 1024 + d0) = ov;
}

// ---------------- sparse gat2 helpers ----------------
__global__ void k_rows2(const int* __restrict__ sid, const int* __restrict__ offs,
                        const int* __restrict__ csr, int* __restrict__ rowlist,
                        int* __restrict__ info) {
  if (threadIdx.x == 0 && blockIdx.x == 0) {
    int pos = 0;
    for (int bv = 0; bv < kB; ++bv) {
      int v = sid[bv];
      int e0 = offs[v], e1 = offs[v + 1];
      info[bv] = pos;
      info[4 + bv] = e1 - e0;
      int self = pos;
      for (int e = e0; e < e1 && pos < kCap; ++e) {
        int s = csr[e];
        if (s == v) self = pos;
        rowlist[pos++] = s;
      }
      info[8 + bv] = self;
    }
    for (int i = pos; i < kCap; ++i) rowlist[i] = 0;
  }
}

__global__ void k_elr_c(const float* __restrict__ fc, const float* __restrict__ al,
                        const float* __restrict__ ar, float* __restrict__ el,
                        float* __restrict__ er) {
  int r = blockIdx.x;
  int lane = threadIdx.x;
  float a = 0.f, b = 0.f;
  for (int d = lane * 4; d < 512; d += 256) {
    float4 x = *(const float4*)(fc + (size_t)r * 512 + d);
    float4 av = *(const float4*)(al + d);
    float4 rv = *(const float4*)(ar + d);
    a += x.x * av.x + x.y * av.y + x.z * av.z + x.w * av.w;
    b += x.x * rv.x + x.y * rv.y + x.z * rv.z + x.w * rv.w;
  }
#pragma unroll
  for (int off = 32; off; off >>= 1) {
    a += __shfl_down(a, off);
    b += __shfl_down(b, off);
  }
  if (lane == 0) { el[r] = a; er[r] = b; }
}

__global__ __launch_bounds__(256) void k_agg_fin2(const float* __restrict__ fc,
                                                  const float* __restrict__ el,
                                                  const float* __restrict__ er,
                                                  const int* __restrict__ info,
                                                  const float* __restrict__ bias,
                                                  float* __restrict__ out) {
  int bv = blockIdx.x;
  int tid = threadIdx.x;
  int start = info[bv], cnt = info[4 + bv];
  float erv = er[info[8 + bv]];
  float m = -1e30f;
  for (int i = 0; i < cnt; ++i) {
    float x = el[start + i] + erv;
    x = x > 0.f ? x : 0.2f * x;
    m = fmaxf(m, x);
  }
  float z = 0.f, a0 = 0.f, a1 = 0.f;
  for (int i = 0; i < cnt; ++i) {
    int r = start + i;
    float x = el[r] + erv;
    x = x > 0.f ? x : 0.2f * x;
    float w = expf(x - m);
    z += w;
    a0 += w * fc[(size_t)r * 512 + tid];
    a1 += w * fc[(size_t)r * 512 + 256 + tid];
  }
  out[bv * 512 + tid] = a0 / z + bias[tid];
  out[bv * 512 + 256 + tid] = a1 / z + bias[256 + tid];
}

// ---------------- launcher ----------------
extern "C" void kernel_launch(void* const* d_in, const int* in_sizes, int n_in,
                              void* d_out, int out_size, void* d_ws, size_t ws_size,
                              hipStream_t stream) {
  const int*   all_words   = (const int*)d_in[0];
  const float* image_feats = (const float*)d_in[1];
  const int*   sentences   = (const int*)d_in[2];
  const float* sent_mask   = (const float*)d_in[3];
  const int*   utterances  = (const int*)d_in[4];
  const float* utt_mask    = (const float*)d_in[5];
  const int*   session_ids = (const int*)d_in[6];
  const int*   edge_src    = (const int*)d_in[7];
  const int*   edge_dst    = (const int*)d_in[8];
  const float* word_embed  = (const float*)d_in[9];
  const float* text_fc_w   = (const float*)d_in[10];
  const float* text_fc_b   = (const float*)d_in[11];
  const float* image_fc_w  = (const float*)d_in[12];
  const float* image_fc_b  = (const float*)d_in[13];
  const float* gat0_fc     = (const float*)d_in[14];
  const float* gat0_al     = (const float*)d_in[15];
  const float* gat0_ar     = (const float*)d_in[16];
  const float* gat0_b      = (const float*)d_in[17];
  const float* gat1_fc     = (const float*)d_in[18];
  const float* gat1_al     = (const float*)d_in[19];
  const float* gat1_ar     = (const float*)d_in[20];
  const float* gat1_b      = (const float*)d_in[21];
  const float* gat2_fc     = (const float*)d_in[22];
  const float* gat2_al     = (const float*)d_in[23];
  const float* gat2_ar     = (const float*)d_in[24];
  const float* gat2_b      = (const float*)d_in[25];

  const int E = in_sizes[7];

  char* base = (char*)d_ws;
  size_t off = 0;
  auto alloc = [&](size_t elems, size_t esz) -> void* {
    void* p = base + off;
    off += ((elems * esz + 255) / 256) * 256;
    return p;
  };
  unsigned short* Abf   = (unsigned short*)alloc((size_t)kN * kHid, 2);
  unsigned short* fbf   = (unsigned short*)alloc((size_t)kN * kHid, 2);
  unsigned short* txtbf = (unsigned short*)alloc((size_t)kTxtRows * kEmbPad, 2);
  unsigned short* imgbf = (unsigned short*)alloc((size_t)kB * kI * 2048, 2);
  unsigned short* wtTx  = (unsigned short*)alloc((size_t)kHid * kEmbPad, 2);
  unsigned short* wtIm  = (unsigned short*)alloc((size_t)kHid * 2048, 2);
  unsigned short* wtG0  = (unsigned short*)alloc((size_t)kHid * kHid, 2);
  unsigned short* wtG1  = (unsigned short*)alloc((size_t)kHid * kHid, 2);
  unsigned short* wtG2  = (unsigned short*)alloc((size_t)kOut * kHid, 2);
  float* Cimg   = (float*)alloc((size_t)kB * kI * kHid, 4);
  float* Cg2    = (float*)alloc((size_t)kCap * kOut, 4);
  float* sentb  = (float*)alloc((size_t)kB * kS * kEmb, 4);
  float* uttb   = (float*)alloc((size_t)kB * kU * kEmb, 4);
  float* sessb  = (float*)alloc((size_t)kB * kEmb, 4);
  float* el     = (float*)alloc((size_t)2 * kN4Pad, 4);   // el + er contiguous
  float* er     = el + kN4Pad;
  float* alphab = (float*)alloc((size_t)E * 4, 4);
  float* zrb    = (float*)alloc((size_t)kN * 4, 4);
  int*   offs   = (int*)alloc(kN + 1, 4);
  int*   cnt    = (int*)alloc(kN, 4);
  int*   csr    = (int*)alloc(E, 4);
  int*   rmt    = (int*)alloc(kTxtRows, 4);
  int*   rmi    = (int*)alloc(kB * kI, 4);
  int*   rowl   = (int*)alloc(kCap, 4);
  int*   info   = (int*)alloc(16, 4);
  (void)ws_size; (void)n_in; (void)out_size;

  // --- feature construction + prep ---
  k_sent<<<kB * kS, 128, 0, stream>>>(sentences, sent_mask, word_embed, sentb);
  k_utt<<<kB * kU, 128, 0, stream>>>(utterances, utt_mask, sentb, uttb);
  k_sess<<<kB, 128, 0, stream>>>(uttb, sessb);
  k_txtgather<<<kTxtRows, 128, 0, stream>>>(all_words, word_embed, sentb, uttb, sessb, txtbf);
  k_rowmap<<<(kTxtRows + 255) / 256, 256, 0, stream>>>(rmt, rmi);
  k_prep<<<5440, dim3(32, 8), 0, stream>>>(text_fc_w, wtTx, image_fc_w, wtIm,
                                           gat0_fc, wtG0, gat1_fc, wtG1, gat2_fc, wtG2,
                                           image_feats, imgbf);

  // --- CSR build ---
  hipMemsetAsync(cnt, 0, kN * sizeof(int), stream);
  k_count<<<(E + 255) / 256, 256, 0, stream>>>(edge_dst, cnt, E);
  k_scan<<<1, 1024, 0, stream>>>(cnt, offs, kN);
  hipMemsetAsync(cnt, 0, kN * sizeof(int), stream);
  k_fill<<<(E + 255) / 256, 256, 0, stream>>>(edge_src, edge_dst, offs, cnt, csr, E);

  // --- text FC (pipelined MFMA, scatter bf16) ---
  k_mm2<true, false><<<dim3(kHid / 128, (kTxtRows + 127) / 128), 256, 0, stream>>>(
      txtbf, wtTx, text_fc_b, rmt, Abf, nullptr, nullptr, nullptr, nullptr,
      kTxtRows, kEmbPad, kHid);

  // --- image FC via split-K ---
  hipMemsetAsync(Cimg, 0, (size_t)kB * kI * kHid * sizeof(float), stream);
  k_mm_sk<<<dim3(kHid / 64, kB * kI / 64, 4), 256, 0, stream>>>(
      imgbf, wtIm, nullptr, Cimg, kB * kI, 2048, kHid, 512);
  k_sk_epi<<<(kB * kI * kHid + 255) / 256, 256, 0, stream>>>(
      Cimg, image_fc_b, rmi, Abf, kB * kI, kHid);

  // --- GAT layer 0 (GEMM + fused el/er) ---
  hipMemsetAsync(el, 0, (size_t)2 * kN4Pad * sizeof(float), stream);
  k_mm2<true, true><<<dim3(kHid / 128, (kN + 127) / 128), 256, 0, stream>>>(
      Abf, wtG0, nullptr, nullptr, fbf, gat0_al, gat0_ar, el, er, kN, kHid, kHid);
  k_alpha<<<(kN * 4 + 255) / 256, 256, 0, stream>>>(el, er, offs, csr, alphab, zrb);
  k_agg2<<<kN, 256, 0, stream>>>(fbf, alphab, zrb, offs, csr, gat0_b, Abf);

  // --- GAT layer 1 ---
  hipMemsetAsync(el, 0, (size_t)2 * kN4Pad * sizeof(float), stream);
  k_mm2<true, true><<<dim3(kHid / 128, (kN + 127) / 128), 256, 0, stream>>>(
      Abf, wtG1, nullptr, nullptr, fbf, gat1_al, gat1_ar, el, er, kN, kHid, kHid);
  k_alpha<<<(kN * 4 + 255) / 256, 256, 0, stream>>>(el, er, offs, csr, alphab, zrb);
  k_agg2<<<kN, 256, 0, stream>>>(fbf, alphab, zrb, offs, csr, gat1_b, Abf);

  // --- GAT layer 2, sparse ---
  k_rows2<<<1, 64, 0, stream>>>(session_ids, offs, csr, rowl, info);
  hipMemsetAsync(Cg2, 0, (size_t)kCap * kOut * sizeof(float), stream);
  k_mm_sk<<<dim3(kOut / 64, kCap / 64, 4), 256, 0, stream>>>(
      Abf, wtG2, rowl, Cg2, kCap, kHid, kOut, 256);
  k_elr_c<<<kCap, 64, 0, stream>>>(Cg2, gat2_al, gat2_ar, el, er);
  k_agg_fin2<<<kB, 256, 0, stream>>>(Cg2, el, er, info, gat2_b, (float*)d_out);
}

// Round 8
// 520.923 us; speedup vs baseline: 1.3101x; 1.3101x over previous
//
#include <hip/hip_runtime.h>
#include <math.h>

// ---------------- problem constants ----------------
constexpr int kB = 4, kW = 2000, kI = 64, kS = 64, kT = 24, kU = 32, kUS = 2;
constexpr int kPER = kW + kI + kS + kU + 1;   // 2161 nodes per graph
constexpr int kN   = kB * kPER;               // 8644 nodes total
constexpr int kTxtPer  = kW + kS + kU + 1;    // 2097 text rows per graph
constexpr int kTxtRows = kB * kTxtPer;        // 8388 text rows
constexpr int kEmb = 300;
constexpr int kEmbPad = 320;
constexpr int kHid = 1024;
constexpr int kOut = 512;
constexpr int kCap = 256;                     // max gathered rows for sparse gat2
constexpr int kN4Pad = 34624;                 // kN*4 rounded up to 256B/4

typedef __attribute__((ext_vector_type(8))) short bf16x8;
typedef __attribute__((ext_vector_type(4))) float f32x4;

__device__ __forceinline__ unsigned short f2bf(float f) {
  union { float f; unsigned int u; } x; x.f = f;
  unsigned int r = x.u + 0x7FFF + ((x.u >> 16) & 1);
  return (unsigned short)(r >> 16);
}
__device__ __forceinline__ float bf2f(unsigned short u) {
  union { unsigned int u; float f; } x; x.u = ((unsigned int)u) << 16;
  return x.f;
}

// ---------------- feature construction (fp32) ----------------

__global__ void k_sent(const int* __restrict__ sents, const float* __restrict__ smask,
                       const float* __restrict__ wemb, float* __restrict__ sent) {
  int bs = blockIdx.x;
  __shared__ int idx[kT];
  __shared__ float mk[kT];
  __shared__ float s_cnt;
  int t = threadIdx.x;
  if (t < kT) { idx[t] = sents[bs * kT + t]; mk[t] = smask[bs * kT + t]; }
  __syncthreads();
  if (t == 0) {
    float c = 0.f;
    for (int i = 0; i < kT; ++i) c += mk[i];
    s_cnt = (c == 0.f) ? 1.f : c;
  }
  __syncthreads();
  for (int d = t; d < kEmb; d += blockDim.x) {
    float acc = 0.f;
    for (int i = 0; i < kT; ++i) acc += wemb[idx[i] * kEmb + d] * mk[i];
    sent[bs * kEmb + d] = acc / s_cnt;
  }
}

__global__ void k_utt(const int* __restrict__ utts, const float* __restrict__ umask,
                      const float* __restrict__ sent, float* __restrict__ utt) {
  int bu = blockIdx.x;
  int b = bu / kU;
  __shared__ int idx[kUS];
  __shared__ float mk[kUS];
  __shared__ float s_cnt;
  int t = threadIdx.x;
  if (t < kUS) { idx[t] = utts[bu * kUS + t]; mk[t] = umask[bu * kUS + t]; }
  __syncthreads();
  if (t == 0) {
    float c = 0.f;
    for (int i = 0; i < kUS; ++i) c += mk[i];
    s_cnt = (c == 0.f) ? 1.f : c;
  }
  __syncthreads();
  for (int d = t; d < kEmb; d += blockDim.x) {
    float acc = 0.f;
    for (int i = 0; i < kUS; ++i) acc += sent[(b * kS + idx[i]) * kEmb + d] * mk[i];
    utt[bu * kEmb + d] = acc / s_cnt;
  }
}

__global__ void k_sess(const float* __restrict__ utt, float* __restrict__ sess) {
  int b = blockIdx.x;
  for (int d = threadIdx.x; d < kEmb; d += blockDim.x) {
    float acc = 0.f;
    for (int u = 0; u < kU; ++u) acc += utt[(b * kU + u) * kEmb + d];
    sess[b * kEmb + d] = acc * (1.f / kU);
  }
}

__global__ void k_txtgather(const int* __restrict__ aw, const float* __restrict__ wemb,
                            const float* __restrict__ sent, const float* __restrict__ utt,
                            const float* __restrict__ sess, unsigned short* __restrict__ txt) {
  int r = blockIdx.x;
  int g = r / kTxtPer, j = r - g * kTxtPer;
  const float* src;
  if (j < kW)                 src = wemb + (size_t)aw[g * kW + j] * kEmb;
  else if (j < kW + kS)       src = sent + (size_t)(g * kS + (j - kW)) * kEmb;
  else if (j < kW + kS + kU)  src = utt  + (size_t)(g * kU + (j - kW - kS)) * kEmb;
  else                        src = sess + (size_t)g * kEmb;
  for (int d = threadIdx.x; d < kEmbPad; d += blockDim.x)
    txt[(size_t)r * kEmbPad + d] = (d < kEmb) ? f2bf(src[d]) : (unsigned short)0;
}

__global__ void k_rowmap(int* __restrict__ rt, int* __restrict__ ri) {
  int i = blockIdx.x * blockDim.x + threadIdx.x;
  if (i < kTxtRows) {
    int g = i / kTxtPer, j = i - g * kTxtPer;
    int base = g * kPER;
    int node;
    if (j < kW)                 node = base + j;
    else if (j < kW + kS)       node = base + kW + kI + (j - kW);
    else if (j < kW + kS + kU)  node = base + kW + kI + kS + (j - kW - kS);
    else                        node = base + kW + kI + kS + kU;
    rt[i] = node;
  }
  if (i < kB * kI) {
    int g = i >> 6;
    ri[i] = g * kPER + kW + (i & 63);
  }
}

// ---------------- fused prep: 5 weight transposes + image f2bf ----------------
__global__ void k_prep(const float* __restrict__ tx_w, unsigned short* __restrict__ o_tx,
                       const float* __restrict__ im_w, unsigned short* __restrict__ o_im,
                       const float* __restrict__ g0_w, unsigned short* __restrict__ o_g0,
                       const float* __restrict__ g1_w, unsigned short* __restrict__ o_g1,
                       const float* __restrict__ g2_w, unsigned short* __restrict__ o_g2,
                       const float* __restrict__ img, unsigned short* __restrict__ o_img) {
  int b = blockIdx.x;
  int tx = threadIdx.x, ty = threadIdx.y;
  const float* in; unsigned short* out; int K, N, Kpad, nbx;
  if (b < 320)               { in = tx_w; out = o_tx; K = kEmb; N = kHid; Kpad = kEmbPad; nbx = 32; }
  else if ((b -= 320) < 2048){ in = im_w; out = o_im; K = 2048; N = kHid; Kpad = 2048; nbx = 32; }
  else if ((b -= 2048) < 1024){ in = g0_w; out = o_g0; K = kHid; N = kHid; Kpad = kHid; nbx = 32; }
  else if ((b -= 1024) < 1024){ in = g1_w; out = o_g1; K = kHid; N = kHid; Kpad = kHid; nbx = 32; }
  else if ((b -= 1024) < 512) { in = g2_w; out = o_g2; K = kHid; N = kOut; Kpad = kHid; nbx = 16; }
  else {
    int i = (b - 512) * 1024 + (ty * 32 + tx) * 4;
    float4 v = *(const float4*)(img + i);
    ushort4 o; o.x = f2bf(v.x); o.y = f2bf(v.y); o.z = f2bf(v.z); o.w = f2bf(v.w);
    *(ushort4*)(o_img + i) = o;
    return;
  }
  int bx = b % nbx, by = b / nbx;
  __shared__ float t[32][33];
  int n = bx * 32 + tx;
#pragma unroll
  for (int j = 0; j < 4; ++j) {
    int k = by * 32 + ty + j * 8;
    t[ty + j * 8][tx] = (k < K) ? in[(size_t)k * N + n] : 0.f;
  }
  __syncthreads();
#pragma unroll
  for (int j = 0; j < 4; ++j) {
    int nn = bx * 32 + ty + j * 8;
    int kk = by * 32 + tx;
    out[(size_t)nn * Kpad + kk] = f2bf(t[tx][ty + j * 8]);
  }
}

// ---------------- bf16 MFMA GEMM (round-4 proven sync staging) + fused el/er ----------------
// 128x128 tile, 4 waves, XOR-swizzled LDS (chunk c of row r at c^(r&7)).
template <bool OBF, bool ELR>
__global__ __launch_bounds__(256) void k_mm2(const unsigned short* __restrict__ A,
                                             const unsigned short* __restrict__ Bt,
                                             const float* __restrict__ bias,
                                             const int* __restrict__ rmap,
                                             void* __restrict__ Cout,
                                             const float* __restrict__ al,
                                             const float* __restrict__ ar,
                                             float* __restrict__ el,
                                             float* __restrict__ er,
                                             int M, int K, int Nc) {
  __shared__ __align__(16) unsigned short As[128 * 64];
  __shared__ __align__(16) unsigned short Bs[128 * 64];
  int tid = threadIdx.x;
  int wid = tid >> 6, lane = tid & 63, quad = lane >> 4, l16 = lane & 15;
  int wm = wid >> 1, wn = wid & 1;
  int row0 = blockIdx.y * 128, col0 = blockIdx.x * 128;

  f32x4 acc[4][4];
  f32x4 zero4 = {0.f, 0.f, 0.f, 0.f};
#pragma unroll
  for (int i = 0; i < 4; ++i)
#pragma unroll
    for (int j = 0; j < 4; ++j) acc[i][j] = zero4;

  int ar_ = tid >> 3;       // 0..31: row within 32-row slab
  int ac = tid & 7;         // 16B chunk index 0..7

  for (int k0 = 0; k0 < K; k0 += 64) {
    __syncthreads();
#pragma unroll
    for (int i = 0; i < 4; ++i) {
      int r = ar_ + i * 32;
      int sw = ((ac ^ (r & 7)) << 3);
      int grow = row0 + r;
      uint4 va = make_uint4(0u, 0u, 0u, 0u);
      if (grow < M) va = *(const uint4*)(A + (size_t)grow * K + k0 + ac * 8);
      *(uint4*)&As[r * 64 + sw] = va;
      int nrow = col0 + r;
      uint4 vb = *(const uint4*)(Bt + (size_t)nrow * K + k0 + ac * 8);
      *(uint4*)&Bs[r * 64 + sw] = vb;
    }
    __syncthreads();
#pragma unroll
    for (int s = 0; s < 2; ++s) {
      int cc = s * 4 + quad;
      bf16x8 aF[4], bF[4];
#pragma unroll
      for (int mi = 0; mi < 4; ++mi) {
        int r = wm * 64 + mi * 16 + l16;
        aF[mi] = *(const bf16x8*)&As[r * 64 + ((cc ^ (r & 7)) << 3)];
      }
#pragma unroll
      for (int ni = 0; ni < 4; ++ni) {
        int r = wn * 64 + ni * 16 + l16;
        bF[ni] = *(const bf16x8*)&Bs[r * 64 + ((cc ^ (r & 7)) << 3)];
      }
#pragma unroll
      for (int mi = 0; mi < 4; ++mi)
#pragma unroll
        for (int ni = 0; ni < 4; ++ni)
          acc[mi][ni] = __builtin_amdgcn_mfma_f32_16x16x32_bf16(aF[mi], bF[ni], acc[mi][ni], 0, 0, 0);
    }
  }

  // ---- epilogue: store (C/D layout: col=lane&15, row=quad*4+reg) ----
#pragma unroll
  for (int mi = 0; mi < 4; ++mi) {
#pragma unroll
    for (int ni = 0; ni < 4; ++ni) {
      int gm0 = row0 + wm * 64 + mi * 16 + quad * 4;
      int gn  = col0 + wn * 64 + ni * 16 + l16;
      float bv = bias ? bias[gn] : 0.f;
#pragma unroll
      for (int i = 0; i < 4; ++i) {
        int r = gm0 + i;
        if (r >= M) continue;
        float v = acc[mi][ni][i] + bv;
        if (OBF) {
          int orow = rmap ? rmap[r] : r;
          ((unsigned short*)Cout)[(size_t)orow * Nc + gn] = f2bf(v);
        } else {
          ((float*)Cout)[(size_t)r * Nc + gn] = v;
        }
      }
    }
  }

  // ---- fused attention logits: this block covers head h = col0>>8 ----
  if (ELR) {
    int h = col0 >> 8;
    float alc[4], arc[4];
#pragma unroll
    for (int ni = 0; ni < 4; ++ni) {
      int c = (col0 & 255) + wn * 64 + ni * 16 + l16;
      alc[ni] = al[h * 256 + c];
      arc[ni] = ar[h * 256 + c];
    }
#pragma unroll
    for (int mi = 0; mi < 4; ++mi) {
#pragma unroll
      for (int i = 0; i < 4; ++i) {
        float se = 0.f, sr = 0.f;
#pragma unroll
        for (int ni = 0; ni < 4; ++ni) {
          float v = acc[mi][ni][i];
          se += v * alc[ni];
          sr += v * arc[ni];
        }
#pragma unroll
        for (int o = 8; o; o >>= 1) {
          se += __shfl_xor(se, o);
          sr += __shfl_xor(sr, o);
        }
        if (l16 == 0) {
          int r = row0 + wm * 64 + mi * 16 + quad * 4 + i;
          if (r < M) {
            atomicAdd(&el[r * 4 + h], se);
            atomicAdd(&er[r * 4 + h], sr);
          }
        }
      }
    }
  }
}

// ---------------- split-K bf16 MFMA GEMM (64x64 tile, optional A-row gather) ----------------
__global__ __launch_bounds__(256) void k_mm_sk(const unsigned short* __restrict__ A,
                                               const unsigned short* __restrict__ Bt,
                                               const int* __restrict__ rowlist,
                                               float* __restrict__ C,
                                               int M, int K, int Nc, int Kc) {
  __shared__ __align__(16) unsigned short As[64 * 64];
  __shared__ __align__(16) unsigned short Bs[64 * 64];
  int tid = threadIdx.x;
  int wid = tid >> 6, lane = tid & 63, quad = lane >> 4, l16 = lane & 15;
  int row0 = blockIdx.y * 64, col0 = blockIdx.x * 64;
  int k0 = blockIdx.z * Kc;
  int k1 = k0 + Kc; if (k1 > K) k1 = K;

  f32x4 acc[4];
  f32x4 zero4 = {0.f, 0.f, 0.f, 0.f};
#pragma unroll
  for (int i = 0; i < 4; ++i) acc[i] = zero4;

  int ar_ = tid >> 3;
  int ac = tid & 7;

  for (int kk = k0; kk < k1; kk += 64) {
    __syncthreads();
#pragma unroll
    for (int i = 0; i < 2; ++i) {
      int r = ar_ + i * 32;
      int sw = ((ac ^ (r & 7)) << 3);
      int grow = row0 + r;
      uint4 va = make_uint4(0u, 0u, 0u, 0u);
      if (grow < M) {
        int arow = rowlist ? rowlist[grow] : grow;
        va = *(const uint4*)(A + (size_t)arow * K + kk + ac * 8);
      }
      *(uint4*)&As[r * 64 + sw] = va;
      int nrow = col0 + r;
      uint4 vb = *(const uint4*)(Bt + (size_t)nrow * K + kk + ac * 8);
      *(uint4*)&Bs[r * 64 + sw] = vb;
    }
    __syncthreads();
#pragma unroll
    for (int s = 0; s < 2; ++s) {
      int cc = s * 4 + quad;
      bf16x8 bF;
      {
        int r = wid * 16 + l16;
        bF = *(const bf16x8*)&Bs[r * 64 + ((cc ^ (r & 7)) << 3)];
      }
#pragma unroll
      for (int mi = 0; mi < 4; ++mi) {
        int r = mi * 16 + l16;
        bf16x8 aF = *(const bf16x8*)&As[r * 64 + ((cc ^ (r & 7)) << 3)];
        acc[mi] = __builtin_amdgcn_mfma_f32_16x16x32_bf16(aF, bF, acc[mi], 0, 0, 0);
      }
    }
  }
#pragma unroll
  for (int mi = 0; mi < 4; ++mi) {
#pragma unroll
    for (int i = 0; i < 4; ++i) {
      int r = row0 + mi * 16 + quad * 4 + i;
      int c = col0 + wid * 16 + l16;
      if (r < M) atomicAdd(&C[(size_t)r * Nc + c], acc[mi][i]);
    }
  }
}

__global__ void k_sk_epi(const float* __restrict__ Cw, const float* __restrict__ bias,
                         const int* __restrict__ rmap, unsigned short* __restrict__ out,
                         int M, int Nc) {
  int i = blockIdx.x * blockDim.x + threadIdx.x;
  if (i >= M * Nc) return;
  int r = i / Nc, c = i - r * Nc;
  out[(size_t)rmap[r] * Nc + c] = f2bf(Cw[i] + bias[c]);
}

// ---------------- CSR build ----------------
__global__ void k_count(const int* __restrict__ dst, int* __restrict__ cnt, int E) {
  int e = blockIdx.x * blockDim.x + threadIdx.x;
  if (e < E) atomicAdd(&cnt[dst[e]], 1);
}

__global__ void k_scan(const int* __restrict__ deg, int* __restrict__ offs, int n) {
  __shared__ int part[1024];
  int tid = threadIdx.x;
  int per = (n + 1023) >> 10;
  int start = tid * per;
  int local = 0;
  for (int i = 0; i < per; ++i) { int idx = start + i; if (idx < n) local += deg[idx]; }
  part[tid] = local;
  __syncthreads();
  for (int off = 1; off < 1024; off <<= 1) {
    int add = (tid >= off) ? part[tid - off] : 0;
    __syncthreads();
    part[tid] += add;
    __syncthreads();
  }
  int run = (tid == 0) ? 0 : part[tid - 1];
  for (int i = 0; i < per; ++i) {
    int idx = start + i;
    if (idx < n) { offs[idx] = run; run += deg[idx]; }
  }
  if (tid == 1023) offs[n] = part[1023];
}

__global__ void k_fill(const int* __restrict__ src, const int* __restrict__ dst,
                       const int* __restrict__ offs, int* __restrict__ cur,
                       int* __restrict__ csr, int E) {
  int e = blockIdx.x * blockDim.x + threadIdx.x;
  if (e < E) {
    int d = dst[e];
    int slot = offs[d] + atomicAdd(&cur[d], 1);
    csr[slot] = src[e];
  }
}

// ---------------- per-edge softmax weights (H=4) ----------------
__global__ void k_alpha(const float* __restrict__ el, const float* __restrict__ er,
                        const int* __restrict__ offs, const int* __restrict__ csr,
                        float* __restrict__ alpha, float* __restrict__ zr) {
  int i = blockIdx.x * blockDim.x + threadIdx.x;
  if (i >= kN * 4) return;
  int v = i >> 2, h = i & 3;
  float erv = er[i];
  int e0 = offs[v], e1 = offs[v + 1];
  float m = -1e30f;
  for (int e = e0; e < e1; ++e) {
    float x = el[csr[e] * 4 + h] + erv;
    x = x > 0.f ? x : 0.2f * x;
    m = fmaxf(m, x);
  }
  float z = 0.f;
  for (int e = e0; e < e1; ++e) {
    float x = el[csr[e] * 4 + h] + erv;
    x = x > 0.f ? x : 0.2f * x;
    float w = expf(x - m);
    z += w;
    alpha[e * 4 + h] = w;
  }
  zr[i] = 1.f / z;
}

// ---------------- aggregation: bf16 gather with precomputed alpha ----------------
__global__ __launch_bounds__(256) void k_agg2(const unsigned short* __restrict__ f,
                                              const float* __restrict__ alpha,
                                              const float* __restrict__ zr,
                                              const int* __restrict__ offs,
                                              const int* __restrict__ csr,
                                              const float* __restrict__ bias,
                                              unsigned short* __restrict__ out) {
  int v = blockIdx.x;
  int tid = threadIdx.x;
  int h = tid >> 6;
  int d0 = tid * 4;
  int e0 = offs[v], e1 = offs[v + 1];
  float a0 = 0.f, a1 = 0.f, a2 = 0.f, a3 = 0.f;
  for (int e = e0; e < e1; ++e) {
    int s = csr[e];
    float w = alpha[e * 4 + h];
    ushort4 fv = *(const ushort4*)(f + (size_t)s * 1024 + d0);
    a0 += w * bf2f(fv.x);
    a1 += w * bf2f(fv.y);
    a2 += w * bf2f(fv.z);
    a3 += w * bf2f(fv.w);
  }
  float rz = zr[v * 4 + h];
  float4 bv = *(const float4*)(bias + d0);
  float o0 = a0 * rz + bv.x, o1 = a1 * rz + bv.y, o2 = a2 * rz + bv.z, o3 = a3 * rz + bv.w;
  o0 = o0 > 0.f ? o0 : expm1f(o0);
  o1 = o1 > 0.f ? o1 : expm1f(o1);
  o2 = o2 > 0.f ? o2 : expm1f(o2);
  o3 = o3 > 0.f ? o3 : expm1f(o3);
  ushort4 ov;
  ov.x = f2bf(o0); ov.y = f2bf(o1); ov.z = f2bf(o2); ov.w = f2bf(o3);
  *(ushort4*)(out + (size_t)v * 1024 + d0) = ov;
}

// ---------------- sparse gat2 helpers ----------------
__global__ void k_rows2(const int* __restrict__ sid, const int* __restrict__ offs,
                        const int* __restrict__ csr, int* __restrict__ rowlist,
                        int* __restrict__ info) {
  if (threadIdx.x == 0 && blockIdx.x == 0) {
    int pos = 0;
    for (int bv = 0; bv < kB; ++bv) {
      int v = sid[bv];
      int e0 = offs[v], e1 = offs[v + 1];
      info[bv] = pos;
      info[4 + bv] = e1 - e0;
      int self = pos;
      for (int e = e0; e < e1 && pos < kCap; ++e) {
        int s = csr[e];
        if (s == v) self = pos;
        rowlist[pos++] = s;
      }
      info[8 + bv] = self;
    }
    for (int i = pos; i < kCap; ++i) rowlist[i] = 0;
  }
}

__global__ void k_elr_c(const float* __restrict__ fc, const float* __restrict__ al,
                        const float* __restrict__ ar, float* __restrict__ el,
                        float* __restrict__ er) {
  int r = blockIdx.x;
  int lane = threadIdx.x;
  float a = 0.f, b = 0.f;
  for (int d = lane * 4; d < 512; d += 256) {
    float4 x = *(const float4*)(fc + (size_t)r * 512 + d);
    float4 av = *(const float4*)(al + d);
    float4 rv = *(const float4*)(ar + d);
    a += x.x * av.x + x.y * av.y + x.z * av.z + x.w * av.w;
    b += x.x * rv.x + x.y * rv.y + x.z * rv.z + x.w * rv.w;
  }
#pragma unroll
  for (int off = 32; off; off >>= 1) {
    a += __shfl_down(a, off);
    b += __shfl_down(b, off);
  }
  if (lane == 0) { el[r] = a; er[r] = b; }
}

__global__ __launch_bounds__(256) void k_agg_fin2(const float* __restrict__ fc,
                                                  const float* __restrict__ el,
                                                  const float* __restrict__ er,
                                                  const int* __restrict__ info,
                                                  const float* __restrict__ bias,
                                                  float* __restrict__ out) {
  int bv = blockIdx.x;
  int tid = threadIdx.x;
  int start = info[bv], cnt = info[4 + bv];
  float erv = er[info[8 + bv]];
  float m = -1e30f;
  for (int i = 0; i < cnt; ++i) {
    float x = el[start + i] + erv;
    x = x > 0.f ? x : 0.2f * x;
    m = fmaxf(m, x);
  }
  float z = 0.f, a0 = 0.f, a1 = 0.f;
  for (int i = 0; i < cnt; ++i) {
    int r = start + i;
    float x = el[r] + erv;
    x = x > 0.f ? x : 0.2f * x;
    float w = expf(x - m);
    z += w;
    a0 += w * fc[(size_t)r * 512 + tid];
    a1 += w * fc[(size_t)r * 512 + 256 + tid];
  }
  out[bv * 512 + tid] = a0 / z + bias[tid];
  out[bv * 512 + 256 + tid] = a1 / z + bias[256 + tid];
}

// ---------------- launcher ----------------
extern "C" void kernel_launch(void* const* d_in, const int* in_sizes, int n_in,
                              void* d_out, int out_size, void* d_ws, size_t ws_size,
                              hipStream_t stream) {
  const int*   all_words   = (const int*)d_in[0];
  const float* image_feats = (const float*)d_in[1];
  const int*   sentences   = (const int*)d_in[2];
  const float* sent_mask   = (const float*)d_in[3];
  const int*   utterances  = (const int*)d_in[4];
  const float* utt_mask    = (const float*)d_in[5];
  const int*   session_ids = (const int*)d_in[6];
  const int*   edge_src    = (const int*)d_in[7];
  const int*   edge_dst    = (const int*)d_in[8];
  const float* word_embed  = (const float*)d_in[9];
  const float* text_fc_w   = (const float*)d_in[10];
  const float* text_fc_b   = (const float*)d_in[11];
  const float* image_fc_w  = (const float*)d_in[12];
  const float* image_fc_b  = (const float*)d_in[13];
  const float* gat0_fc     = (const float*)d_in[14];
  const float* gat0_al     = (const float*)d_in[15];
  const float* gat0_ar     = (const float*)d_in[16];
  const float* gat0_b      = (const float*)d_in[17];
  const float* gat1_fc     = (const float*)d_in[18];
  const float* gat1_al     = (const float*)d_in[19];
  const float* gat1_ar     = (const float*)d_in[20];
  const float* gat1_b      = (const float*)d_in[21];
  const float* gat2_fc     = (const float*)d_in[22];
  const float* gat2_al     = (const float*)d_in[23];
  const float* gat2_ar     = (const float*)d_in[24];
  const float* gat2_b      = (const float*)d_in[25];

  const int E = in_sizes[7];

  char* base = (char*)d_ws;
  size_t off = 0;
  auto alloc = [&](size_t elems, size_t esz) -> void* {
    void* p = base + off;
    off += ((elems * esz + 255) / 256) * 256;
    return p;
  };
  unsigned short* Abf   = (unsigned short*)alloc((size_t)kN * kHid, 2);
  unsigned short* fbf   = (unsigned short*)alloc((size_t)kN * kHid, 2);
  unsigned short* txtbf = (unsigned short*)alloc((size_t)kTxtRows * kEmbPad, 2);
  unsigned short* imgbf = (unsigned short*)alloc((size_t)kB * kI * 2048, 2);
  unsigned short* wtTx  = (unsigned short*)alloc((size_t)kHid * kEmbPad, 2);
  unsigned short* wtIm  = (unsigned short*)alloc((size_t)kHid * 2048, 2);
  unsigned short* wtG0  = (unsigned short*)alloc((size_t)kHid * kHid, 2);
  unsigned short* wtG1  = (unsigned short*)alloc((size_t)kHid * kHid, 2);
  unsigned short* wtG2  = (unsigned short*)alloc((size_t)kOut * kHid, 2);
  float* Cimg   = (float*)alloc((size_t)kB * kI * kHid, 4);
  float* Cg2    = (float*)alloc((size_t)kCap * kOut, 4);
  float* sentb  = (float*)alloc((size_t)kB * kS * kEmb, 4);
  float* uttb   = (float*)alloc((size_t)kB * kU * kEmb, 4);
  float* sessb  = (float*)alloc((size_t)kB * kEmb, 4);
  float* el     = (float*)alloc((size_t)2 * kN4Pad, 4);   // el + er contiguous
  float* er     = el + kN4Pad;
  float* alphab = (float*)alloc((size_t)E * 4, 4);
  float* zrb    = (float*)alloc((size_t)kN * 4, 4);
  int*   offs   = (int*)alloc(kN + 1, 4);
  int*   cnt    = (int*)alloc(kN, 4);
  int*   csr    = (int*)alloc(E, 4);
  int*   rmt    = (int*)alloc(kTxtRows, 4);
  int*   rmi    = (int*)alloc(kB * kI, 4);
  int*   rowl   = (int*)alloc(kCap, 4);
  int*   info   = (int*)alloc(16, 4);
  (void)ws_size; (void)n_in; (void)out_size;

  // --- feature construction + prep ---
  k_sent<<<kB * kS, 128, 0, stream>>>(sentences, sent_mask, word_embed, sentb);
  k_utt<<<kB * kU, 128, 0, stream>>>(utterances, utt_mask, sentb, uttb);
  k_sess<<<kB, 128, 0, stream>>>(uttb, sessb);
  k_txtgather<<<kTxtRows, 128, 0, stream>>>(all_words, word_embed, sentb, uttb, sessb, txtbf);
  k_rowmap<<<(kTxtRows + 255) / 256, 256, 0, stream>>>(rmt, rmi);
  k_prep<<<5440, dim3(32, 8), 0, stream>>>(text_fc_w, wtTx, image_fc_w, wtIm,
                                           gat0_fc, wtG0, gat1_fc, wtG1, gat2_fc, wtG2,
                                           image_feats, imgbf);

  // --- CSR build ---
  hipMemsetAsync(cnt, 0, kN * sizeof(int), stream);
  k_count<<<(E + 255) / 256, 256, 0, stream>>>(edge_dst, cnt, E);
  k_scan<<<1, 1024, 0, stream>>>(cnt, offs, kN);
  hipMemsetAsync(cnt, 0, kN * sizeof(int), stream);
  k_fill<<<(E + 255) / 256, 256, 0, stream>>>(edge_src, edge_dst, offs, cnt, csr, E);

  // --- text FC (MFMA, scatter bf16) ---
  k_mm2<true, false><<<dim3(kHid / 128, (kTxtRows + 127) / 128), 256, 0, stream>>>(
      txtbf, wtTx, text_fc_b, rmt, Abf, nullptr, nullptr, nullptr, nullptr,
      kTxtRows, kEmbPad, kHid);

  // --- image FC via split-K ---
  hipMemsetAsync(Cimg, 0, (size_t)kB * kI * kHid * sizeof(float), stream);
  k_mm_sk<<<dim3(kHid / 64, kB * kI / 64, 4), 256, 0, stream>>>(
      imgbf, wtIm, nullptr, Cimg, kB * kI, 2048, kHid, 512);
  k_sk_epi<<<(kB * kI * kHid + 255) / 256, 256, 0, stream>>>(
      Cimg, image_fc_b, rmi, Abf, kB * kI, kHid);

  // --- GAT layer 0 (GEMM + fused el/er) ---
  hipMemsetAsync(el, 0, (size_t)2 * kN4Pad * sizeof(float), stream);
  k_mm2<true, true><<<dim3(kHid / 128, (kN + 127) / 128), 256, 0, stream>>>(
      Abf, wtG0, nullptr, nullptr, fbf, gat0_al, gat0_ar, el, er, kN, kHid, kHid);
  k_alpha<<<(kN * 4 + 255) / 256, 256, 0, stream>>>(el, er, offs, csr, alphab, zrb);
  k_agg2<<<kN, 256, 0, stream>>>(fbf, alphab, zrb, offs, csr, gat0_b, Abf);

  // --- GAT layer 1 ---
  hipMemsetAsync(el, 0, (size_t)2 * kN4Pad * sizeof(float), stream);
  k_mm2<true, true><<<dim3(kHid / 128, (kN + 127) / 128), 256, 0, stream>>>(
      Abf, wtG1, nullptr, nullptr, fbf, gat1_al, gat1_ar, el, er, kN, kHid, kHid);
  k_alpha<<<(kN * 4 + 255) / 256, 256, 0, stream>>>(el, er, offs, csr, alphab, zrb);
  k_agg2<<<kN, 256, 0, stream>>>(fbf, alphab, zrb, offs, csr, gat1_b, Abf);

  // --- GAT layer 2, sparse ---
  k_rows2<<<1, 64, 0, stream>>>(session_ids, offs, csr, rowl, info);
  hipMemsetAsync(Cg2, 0, (size_t)kCap * kOut * sizeof(float), stream);
  k_mm_sk<<<dim3(kOut / 64, kCap / 64, 4), 256, 0, stream>>>(
      Abf, wtG2, rowl, Cg2, kCap, kHid, kOut, 256);
  k_elr_c<<<kCap, 64, 0, stream>>>(Cg2, gat2_al, gat2_ar, el, er);
  k_agg_fin2<<<kB, 256, 0, stream>>>(Cg2, el, er, info, gat2_b, (float*)d_out);
}

// Round 9
// 452.360 us; speedup vs baseline: 1.5086x; 1.1516x over previous
//
#include <hip/hip_runtime.h>
#include <math.h>

// ---------------- problem constants ----------------
constexpr int kB = 4, kW = 2000, kI = 64, kS = 64, kT = 24, kU = 32, kUS = 2;
constexpr int kPER = kW + kI + kS + kU + 1;   // 2161 nodes per graph
constexpr int kN   = kB * kPER;               // 8644 nodes total
constexpr int kTxtPer  = kW + kS + kU + 1;    // 2097 text rows per graph
constexpr int kTxtRows = kB * kTxtPer;        // 8388 text rows
constexpr int kEmb = 300;
constexpr int kEmbPad = 320;
constexpr int kHid = 1024;
constexpr int kOut = 512;
constexpr int kCap = 256;                     // max gathered rows for sparse gat2
constexpr int kMaxDeg = 256;                  // softmax LDS capacity per head

typedef __attribute__((ext_vector_type(8))) short bf16x8;
typedef __attribute__((ext_vector_type(4))) float f32x4;

__device__ __forceinline__ unsigned short f2bf(float f) {
  union { float f; unsigned int u; } x; x.f = f;
  unsigned int r = x.u + 0x7FFF + ((x.u >> 16) & 1);
  return (unsigned short)(r >> 16);
}
__device__ __forceinline__ float bf2f(unsigned short u) {
  union { unsigned int u; float f; } x; x.u = ((unsigned int)u) << 16;
  return x.f;
}

// ---------------- feature construction (fp32) ----------------

__global__ void k_sent(const int* __restrict__ sents, const float* __restrict__ smask,
                       const float* __restrict__ wemb, float* __restrict__ sent) {
  int bs = blockIdx.x;
  __shared__ int idx[kT];
  __shared__ float mk[kT];
  __shared__ float s_cnt;
  int t = threadIdx.x;
  if (t < kT) { idx[t] = sents[bs * kT + t]; mk[t] = smask[bs * kT + t]; }
  __syncthreads();
  if (t == 0) {
    float c = 0.f;
    for (int i = 0; i < kT; ++i) c += mk[i];
    s_cnt = (c == 0.f) ? 1.f : c;
  }
  __syncthreads();
  for (int d = t; d < kEmb; d += blockDim.x) {
    float acc = 0.f;
    for (int i = 0; i < kT; ++i) acc += wemb[idx[i] * kEmb + d] * mk[i];
    sent[bs * kEmb + d] = acc / s_cnt;
  }
}

__global__ void k_utt(const int* __restrict__ utts, const float* __restrict__ umask,
                      const float* __restrict__ sent, float* __restrict__ utt) {
  int bu = blockIdx.x;
  int b = bu / kU;
  __shared__ int idx[kUS];
  __shared__ float mk[kUS];
  __shared__ float s_cnt;
  int t = threadIdx.x;
  if (t < kUS) { idx[t] = utts[bu * kUS + t]; mk[t] = umask[bu * kUS + t]; }
  __syncthreads();
  if (t == 0) {
    float c = 0.f;
    for (int i = 0; i < kUS; ++i) c += mk[i];
    s_cnt = (c == 0.f) ? 1.f : c;
  }
  __syncthreads();
  for (int d = t; d < kEmb; d += blockDim.x) {
    float acc = 0.f;
    for (int i = 0; i < kUS; ++i) acc += sent[(b * kS + idx[i]) * kEmb + d] * mk[i];
    utt[bu * kEmb + d] = acc / s_cnt;
  }
}

__global__ void k_sess(const float* __restrict__ utt, float* __restrict__ sess) {
  int b = blockIdx.x;
  for (int d = threadIdx.x; d < kEmb; d += blockDim.x) {
    float acc = 0.f;
    for (int u = 0; u < kU; ++u) acc += utt[(b * kU + u) * kEmb + d];
    sess[b * kEmb + d] = acc * (1.f / kU);
  }
}

__global__ void k_txtgather(const int* __restrict__ aw, const float* __restrict__ wemb,
                            const float* __restrict__ sent, const float* __restrict__ utt,
                            const float* __restrict__ sess, unsigned short* __restrict__ txt) {
  int r = blockIdx.x;
  int g = r / kTxtPer, j = r - g * kTxtPer;
  const float* src;
  if (j < kW)                 src = wemb + (size_t)aw[g * kW + j] * kEmb;
  else if (j < kW + kS)       src = sent + (size_t)(g * kS + (j - kW)) * kEmb;
  else if (j < kW + kS + kU)  src = utt  + (size_t)(g * kU + (j - kW - kS)) * kEmb;
  else                        src = sess + (size_t)g * kEmb;
  for (int d = threadIdx.x; d < kEmbPad; d += blockDim.x)
    txt[(size_t)r * kEmbPad + d] = (d < kEmb) ? f2bf(src[d]) : (unsigned short)0;
}

__global__ void k_rowmap(int* __restrict__ rt, int* __restrict__ ri) {
  int i = blockIdx.x * blockDim.x + threadIdx.x;
  if (i < kTxtRows) {
    int g = i / kTxtPer, j = i - g * kTxtPer;
    int base = g * kPER;
    int node;
    if (j < kW)                 node = base + j;
    else if (j < kW + kS)       node = base + kW + kI + (j - kW);
    else if (j < kW + kS + kU)  node = base + kW + kI + kS + (j - kW - kS);
    else                        node = base + kW + kI + kS + kU;
    rt[i] = node;
  }
  if (i < kB * kI) {
    int g = i >> 6;
    ri[i] = g * kPER + kW + (i & 63);
  }
}

// ---------------- fused prep: 5 weight transposes + image f2bf ----------------
__global__ void k_prep(const float* __restrict__ tx_w, unsigned short* __restrict__ o_tx,
                       const float* __restrict__ im_w, unsigned short* __restrict__ o_im,
                       const float* __restrict__ g0_w, unsigned short* __restrict__ o_g0,
                       const float* __restrict__ g1_w, unsigned short* __restrict__ o_g1,
                       const float* __restrict__ g2_w, unsigned short* __restrict__ o_g2,
                       const float* __restrict__ img, unsigned short* __restrict__ o_img) {
  int b = blockIdx.x;
  int tx = threadIdx.x, ty = threadIdx.y;
  const float* in; unsigned short* out; int K, N, Kpad, nbx;
  if (b < 320)               { in = tx_w; out = o_tx; K = kEmb; N = kHid; Kpad = kEmbPad; nbx = 32; }
  else if ((b -= 320) < 2048){ in = im_w; out = o_im; K = 2048; N = kHid; Kpad = 2048; nbx = 32; }
  else if ((b -= 2048) < 1024){ in = g0_w; out = o_g0; K = kHid; N = kHid; Kpad = kHid; nbx = 32; }
  else if ((b -= 1024) < 1024){ in = g1_w; out = o_g1; K = kHid; N = kHid; Kpad = kHid; nbx = 32; }
  else if ((b -= 1024) < 512) { in = g2_w; out = o_g2; K = kHid; N = kOut; Kpad = kHid; nbx = 16; }
  else {
    int i = (b - 512) * 1024 + (ty * 32 + tx) * 4;
    float4 v = *(const float4*)(img + i);
    ushort4 o; o.x = f2bf(v.x); o.y = f2bf(v.y); o.z = f2bf(v.z); o.w = f2bf(v.w);
    *(ushort4*)(o_img + i) = o;
    return;
  }
  int bx = b % nbx, by = b / nbx;
  __shared__ float t[32][33];
  int n = bx * 32 + tx;
#pragma unroll
  for (int j = 0; j < 4; ++j) {
    int k = by * 32 + ty + j * 8;
    t[ty + j * 8][tx] = (k < K) ? in[(size_t)k * N + n] : 0.f;
  }
  __syncthreads();
#pragma unroll
  for (int j = 0; j < 4; ++j) {
    int nn = bx * 32 + ty + j * 8;
    int kk = by * 32 + tx;
    out[(size_t)nn * Kpad + kk] = f2bf(t[tx][ty + j * 8]);
  }
}

// ---------------- bf16 MFMA GEMM (round-4 proven sync staging) ----------------
// 128x128 tile, 4 waves, XOR-swizzled LDS (chunk c of row r at c^(r&7)).
template <bool OBF>
__global__ __launch_bounds__(256) void k_mm2(const unsigned short* __restrict__ A,
                                             const unsigned short* __restrict__ Bt,
                                             const float* __restrict__ bias,
                                             const int* __restrict__ rmap,
                                             void* __restrict__ Cout,
                                             int M, int K, int Nc) {
  __shared__ __align__(16) unsigned short As[128 * 64];
  __shared__ __align__(16) unsigned short Bs[128 * 64];
  int tid = threadIdx.x;
  int wid = tid >> 6, lane = tid & 63, quad = lane >> 4, l16 = lane & 15;
  int wm = wid >> 1, wn = wid & 1;
  int row0 = blockIdx.y * 128, col0 = blockIdx.x * 128;

  f32x4 acc[4][4];
  f32x4 zero4 = {0.f, 0.f, 0.f, 0.f};
#pragma unroll
  for (int i = 0; i < 4; ++i)
#pragma unroll
    for (int j = 0; j < 4; ++j) acc[i][j] = zero4;

  int ar_ = tid >> 3;       // 0..31: row within 32-row slab
  int ac = tid & 7;         // 16B chunk index 0..7

  for (int k0 = 0; k0 < K; k0 += 64) {
    __syncthreads();
#pragma unroll
    for (int i = 0; i < 4; ++i) {
      int r = ar_ + i * 32;
      int sw = ((ac ^ (r & 7)) << 3);
      int grow = row0 + r;
      uint4 va = make_uint4(0u, 0u, 0u, 0u);
      if (grow < M) va = *(const uint4*)(A + (size_t)grow * K + k0 + ac * 8);
      *(uint4*)&As[r * 64 + sw] = va;
      int nrow = col0 + r;
      uint4 vb = *(const uint4*)(Bt + (size_t)nrow * K + k0 + ac * 8);
      *(uint4*)&Bs[r * 64 + sw] = vb;
    }
    __syncthreads();
#pragma unroll
    for (int s = 0; s < 2; ++s) {
      int cc = s * 4 + quad;
      bf16x8 aF[4], bF[4];
#pragma unroll
      for (int mi = 0; mi < 4; ++mi) {
        int r = wm * 64 + mi * 16 + l16;
        aF[mi] = *(const bf16x8*)&As[r * 64 + ((cc ^ (r & 7)) << 3)];
      }
#pragma unroll
      for (int ni = 0; ni < 4; ++ni) {
        int r = wn * 64 + ni * 16 + l16;
        bF[ni] = *(const bf16x8*)&Bs[r * 64 + ((cc ^ (r & 7)) << 3)];
      }
#pragma unroll
      for (int mi = 0; mi < 4; ++mi)
#pragma unroll
        for (int ni = 0; ni < 4; ++ni)
          acc[mi][ni] = __builtin_amdgcn_mfma_f32_16x16x32_bf16(aF[mi], bF[ni], acc[mi][ni], 0, 0, 0);
    }
  }

  // ---- epilogue: store (C/D layout: col=lane&15, row=quad*4+reg) ----
#pragma unroll
  for (int mi = 0; mi < 4; ++mi) {
#pragma unroll
    for (int ni = 0; ni < 4; ++ni) {
      int gm0 = row0 + wm * 64 + mi * 16 + quad * 4;
      int gn  = col0 + wn * 64 + ni * 16 + l16;
      float bv = bias ? bias[gn] : 0.f;
#pragma unroll
      for (int i = 0; i < 4; ++i) {
        int r = gm0 + i;
        if (r >= M) continue;
        float v = acc[mi][ni][i] + bv;
        if (OBF) {
          int orow = rmap ? rmap[r] : r;
          ((unsigned short*)Cout)[(size_t)orow * Nc + gn] = f2bf(v);
        } else {
          ((float*)Cout)[(size_t)r * Nc + gn] = v;
        }
      }
    }
  }
}

// ---------------- attention logits, bf16 f, H=4 D=256 ----------------
__global__ void k_elr4(const unsigned short* __restrict__ f, const float* __restrict__ al,
                       const float* __restrict__ ar, float* __restrict__ el,
                       float* __restrict__ er) {
  int v = blockIdx.x;
  int h = threadIdx.x >> 6, lane = threadIdx.x & 63;
  int d = lane * 4;
  ushort4 fv = *(const ushort4*)(f + (size_t)v * 1024 + h * 256 + d);
  float4 av = *(const float4*)(al + h * 256 + d);
  float4 rv = *(const float4*)(ar + h * 256 + d);
  float x0 = bf2f(fv.x), x1 = bf2f(fv.y), x2 = bf2f(fv.z), x3 = bf2f(fv.w);
  float a = x0 * av.x + x1 * av.y + x2 * av.z + x3 * av.w;
  float b = x0 * rv.x + x1 * rv.y + x2 * rv.z + x3 * rv.w;
#pragma unroll
  for (int off = 32; off; off >>= 1) {
    a += __shfl_down(a, off);
    b += __shfl_down(b, off);
  }
  if (lane == 0) { el[v * 4 + h] = a; er[v * 4 + h] = b; }
}

// ---------------- split-K bf16 MFMA GEMM (64x64 tile, optional A-row gather) ----------------
__global__ __launch_bounds__(256) void k_mm_sk(const unsigned short* __restrict__ A,
                                               const unsigned short* __restrict__ Bt,
                                               const int* __restrict__ rowlist,
                                               float* __restrict__ C,
                                               int M, int K, int Nc, int Kc) {
  __shared__ __align__(16) unsigned short As[64 * 64];
  __shared__ __align__(16) unsigned short Bs[64 * 64];
  int tid = threadIdx.x;
  int wid = tid >> 6, lane = tid & 63, quad = lane >> 4, l16 = lane & 15;
  int row0 = blockIdx.y * 64, col0 = blockIdx.x * 64;
  int k0 = blockIdx.z * Kc;
  int k1 = k0 + Kc; if (k1 > K) k1 = K;

  f32x4 acc[4];
  f32x4 zero4 = {0.f, 0.f, 0.f, 0.f};
#pragma unroll
  for (int i = 0; i < 4; ++i) acc[i] = zero4;

  int ar_ = tid >> 3;
  int ac = tid & 7;

  for (int kk = k0; kk < k1; kk += 64) {
    __syncthreads();
#pragma unroll
    for (int i = 0; i < 2; ++i) {
      int r = ar_ + i * 32;
      int sw = ((ac ^ (r & 7)) << 3);
      int grow = row0 + r;
      uint4 va = make_uint4(0u, 0u, 0u, 0u);
      if (grow < M) {
        int arow = rowlist ? rowlist[grow] : grow;
        va = *(const uint4*)(A + (size_t)arow * K + kk + ac * 8);
      }
      *(uint4*)&As[r * 64 + sw] = va;
      int nrow = col0 + r;
      uint4 vb = *(const uint4*)(Bt + (size_t)nrow * K + kk + ac * 8);
      *(uint4*)&Bs[r * 64 + sw] = vb;
    }
    __syncthreads();
#pragma unroll
    for (int s = 0; s < 2; ++s) {
      int cc = s * 4 + quad;
      bf16x8 bF;
      {
        int r = wid * 16 + l16;
        bF = *(const bf16x8*)&Bs[r * 64 + ((cc ^ (r & 7)) << 3)];
      }
#pragma unroll
      for (int mi = 0; mi < 4; ++mi) {
        int r = mi * 16 + l16;
        bf16x8 aF = *(const bf16x8*)&As[r * 64 + ((cc ^ (r & 7)) << 3)];
        acc[mi] = __builtin_amdgcn_mfma_f32_16x16x32_bf16(aF, bF, acc[mi], 0, 0, 0);
      }
    }
  }
#pragma unroll
  for (int mi = 0; mi < 4; ++mi) {
#pragma unroll
    for (int i = 0; i < 4; ++i) {
      int r = row0 + mi * 16 + quad * 4 + i;
      int c = col0 + wid * 16 + l16;
      if (r < M) atomicAdd(&C[(size_t)r * Nc + c], acc[mi][i]);
    }
  }
}

__global__ void k_sk_epi(const float* __restrict__ Cw, const float* __restrict__ bias,
                         const int* __restrict__ rmap, unsigned short* __restrict__ out,
                         int M, int Nc) {
  int i = blockIdx.x * blockDim.x + threadIdx.x;
  if (i >= M * Nc) return;
  int r = i / Nc, c = i - r * Nc;
  out[(size_t)rmap[r] * Nc + c] = f2bf(Cw[i] + bias[c]);
}

// ---------------- CSR build ----------------
__global__ void k_count(const int* __restrict__ dst, int* __restrict__ cnt, int E) {
  int e = blockIdx.x * blockDim.x + threadIdx.x;
  if (e < E) atomicAdd(&cnt[dst[e]], 1);
}

__global__ void k_scan(const int* __restrict__ deg, int* __restrict__ offs, int n) {
  __shared__ int part[1024];
  int tid = threadIdx.x;
  int per = (n + 1023) >> 10;
  int start = tid * per;
  int local = 0;
  for (int i = 0; i < per; ++i) { int idx = start + i; if (idx < n) local += deg[idx]; }
  part[tid] = local;
  __syncthreads();
  for (int off = 1; off < 1024; off <<= 1) {
    int add = (tid >= off) ? part[tid - off] : 0;
    __syncthreads();
    part[tid] += add;
    __syncthreads();
  }
  int run = (tid == 0) ? 0 : part[tid - 1];
  for (int i = 0; i < per; ++i) {
    int idx = start + i;
    if (idx < n) { offs[idx] = run; run += deg[idx]; }
  }
  if (tid == 1023) offs[n] = part[1023];
}

__global__ void k_fill(const int* __restrict__ src, const int* __restrict__ dst,
                       const int* __restrict__ offs, int* __restrict__ cur,
                       int* __restrict__ csr, int E) {
  int e = blockIdx.x * blockDim.x + threadIdx.x;
  if (e < E) {
    int d = dst[e];
    int slot = offs[d] + atomicAdd(&cur[d], 1);
    csr[slot] = src[e];
  }
}

// ---------------- fused softmax + aggregation (H=4, D=256, ELU, bf16 in/out) ----------------
// One block per dst node. Wave h computes head-h softmax weights lane-parallel into
// LDS, then all 256 threads do the alpha-weighted gather of f[src].
__global__ __launch_bounds__(256) void k_agg3(const unsigned short* __restrict__ f,
                                              const float* __restrict__ el,
                                              const float* __restrict__ er,
                                              const int* __restrict__ offs,
                                              const int* __restrict__ csr,
                                              const float* __restrict__ bias,
                                              unsigned short* __restrict__ out) {
  __shared__ float xs[4][kMaxDeg];
  int v = blockIdx.x;
  int tid = threadIdx.x;
  int h = tid >> 6, lane = tid & 63;
  int e0 = offs[v];
  int deg = offs[v + 1] - e0;
  if (deg > kMaxDeg) deg = kMaxDeg;

  // ---- stage 1 (per-wave, lane-parallel over edges): softmax weights -> LDS ----
  float erv = er[v * 4 + h];
  float m = -1e30f;
  for (int base = 0; base < deg; base += 64) {
    int idx = base + lane;
    float x = -1e30f;
    if (idx < deg) {
      int s = csr[e0 + idx];
      x = el[s * 4 + h] + erv;
      x = x > 0.f ? x : 0.2f * x;
      xs[h][idx] = x;
    }
    float mm = x;
#pragma unroll
    for (int o = 32; o; o >>= 1) mm = fmaxf(mm, __shfl_xor(mm, o));
    m = fmaxf(m, mm);
  }
  float zs = 0.f;
  for (int base = 0; base < deg; base += 64) {
    int idx = base + lane;
    if (idx < deg) {
      float w = expf(xs[h][idx] - m);
      xs[h][idx] = w;
      zs += w;
    }
  }
#pragma unroll
  for (int o = 32; o; o >>= 1) zs += __shfl_xor(zs, o);
  float rz = 1.f / zs;
  for (int base = 0; base < deg; base += 64) {
    int idx = base + lane;
    if (idx < deg) xs[h][idx] *= rz;
  }
  __syncthreads();

  // ---- stage 2 (all threads): weighted gather ----
  int d0 = tid * 4;
  float a0 = 0.f, a1 = 0.f, a2 = 0.f, a3 = 0.f;
  for (int e = 0; e < deg; ++e) {
    int s = csr[e0 + e];
    float w = xs[h][e];
    ushort4 fv = *(const ushort4*)(f + (size_t)s * 1024 + d0);
    a0 += w * bf2f(fv.x);
    a1 += w * bf2f(fv.y);
    a2 += w * bf2f(fv.z);
    a3 += w * bf2f(fv.w);
  }
  float4 bv = *(const float4*)(bias + d0);
  float o0 = a0 + bv.x, o1 = a1 + bv.y, o2 = a2 + bv.z, o3 = a3 + bv.w;
  o0 = o0 > 0.f ? o0 : expm1f(o0);
  o1 = o1 > 0.f ? o1 : expm1f(o1);
  o2 = o2 > 0.f ? o2 : expm1f(o2);
  o3 = o3 > 0.f ? o3 : expm1f(o3);
  ushort4 ov;
  ov.x = f2bf(o0); ov.y = f2bf(o1); ov.z = f2bf(o2); ov.w = f2bf(o3);
  *(ushort4*)(out + (size_t)v * 1024 + d0) = ov;
}

// ---------------- sparse gat2 helpers ----------------
__global__ void k_rows2(const int* __restrict__ sid, const int* __restrict__ offs,
                        const int* __restrict__ csr, int* __restrict__ rowlist,
                        int* __restrict__ info) {
  if (threadIdx.x == 0 && blockIdx.x == 0) {
    int pos = 0;
    for (int bv = 0; bv < kB; ++bv) {
      int v = sid[bv];
      int e0 = offs[v], e1 = offs[v + 1];
      info[bv] = pos;
      info[4 + bv] = e1 - e0;
      int self = pos;
      for (int e = e0; e < e1 && pos < kCap; ++e) {
        int s = csr[e];
        if (s == v) self = pos;
        rowlist[pos++] = s;
      }
      info[8 + bv] = self;
    }
    for (int i = pos; i < kCap; ++i) rowlist[i] = 0;
  }
}

__global__ void k_elr_c(const float* __restrict__ fc, const float* __restrict__ al,
                        const float* __restrict__ ar, float* __restrict__ el,
                        float* __restrict__ er) {
  int r = blockIdx.x;
  int lane = threadIdx.x;
  float a = 0.f, b = 0.f;
  for (int d = lane * 4; d < 512; d += 256) {
    float4 x = *(const float4*)(fc + (size_t)r * 512 + d);
    float4 av = *(const float4*)(al + d);
    float4 rv = *(const float4*)(ar + d);
    a += x.x * av.x + x.y * av.y + x.z * av.z + x.w * av.w;
    b += x.x * rv.x + x.y * rv.y + x.z * rv.z + x.w * rv.w;
  }
#pragma unroll
  for (int off = 32; off; off >>= 1) {
    a += __shfl_down(a, off);
    b += __shfl_down(b, off);
  }
  if (lane == 0) { el[r] = a; er[r] = b; }
}

__global__ __launch_bounds__(256) void k_agg_fin2(const float* __restrict__ fc,
                                                  const float* __restrict__ el,
                                                  const float* __restrict__ er,
                                                  const int* __restrict__ info,
                                                  const float* __restrict__ bias,
                                                  float* __restrict__ out) {
  int bv = blockIdx.x;
  int tid = threadIdx.x;
  int start = info[bv], cnt = info[4 + bv];
  float erv = er[info[8 + bv]];
  float m = -1e30f;
  for (int i = 0; i < cnt; ++i) {
    float x = el[start + i] + erv;
    x = x > 0.f ? x : 0.2f * x;
    m = fmaxf(m, x);
  }
  float z = 0.f, a0 = 0.f, a1 = 0.f;
  for (int i = 0; i < cnt; ++i) {
    int r = start + i;
    float x = el[r] + erv;
    x = x > 0.f ? x : 0.2f * x;
    float w = expf(x - m);
    z += w;
    a0 += w * fc[(size_t)r * 512 + tid];
    a1 += w * fc[(size_t)r * 512 + 256 + tid];
  }
  out[bv * 512 + tid] = a0 / z + bias[tid];
  out[bv * 512 + 256 + tid] = a1 / z + bias[256 + tid];
}

// ---------------- launcher ----------------
extern "C" void kernel_launch(void* const* d_in, const int* in_sizes, int n_in,
                              void* d_out, int out_size, void* d_ws, size_t ws_size,
                              hipStream_t stream) {
  const int*   all_words   = (const int*)d_in[0];
  const float* image_feats = (const float*)d_in[1];
  const int*   sentences   = (const int*)d_in[2];
  const float* sent_mask   = (const float*)d_in[3];
  const int*   utterances  = (const int*)d_in[4];
  const float* utt_mask    = (const float*)d_in[5];
  const int*   session_ids = (const int*)d_in[6];
  const int*   edge_src    = (const int*)d_in[7];
  const int*   edge_dst    = (const int*)d_in[8];
  const float* word_embed  = (const float*)d_in[9];
  const float* text_fc_w   = (const float*)d_in[10];
  const float* text_fc_b   = (const float*)d_in[11];
  const float* image_fc_w  = (const float*)d_in[12];
  const float* image_fc_b  = (const float*)d_in[13];
  const float* gat0_fc     = (const float*)d_in[14];
  const float* gat0_al     = (const float*)d_in[15];
  const float* gat0_ar     = (const float*)d_in[16];
  const float* gat0_b      = (const float*)d_in[17];
  const float* gat1_fc     = (const float*)d_in[18];
  const float* gat1_al     = (const float*)d_in[19];
  const float* gat1_ar     = (const float*)d_in[20];
  const float* gat1_b      = (const float*)d_in[21];
  const float* gat2_fc     = (const float*)d_in[22];
  const float* gat2_al     = (const float*)d_in[23];
  const float* gat2_ar     = (const float*)d_in[24];
  const float* gat2_b      = (const float*)d_in[25];

  const int E = in_sizes[7];

  char* base = (char*)d_ws;
  size_t off = 0;
  auto alloc = [&](size_t elems, size_t esz) -> void* {
    void* p = base + off;
    off += ((elems * esz + 255) / 256) * 256;
    return p;
  };
  unsigned short* Abf   = (unsigned short*)alloc((size_t)kN * kHid, 2);
  unsigned short* fbf   = (unsigned short*)alloc((size_t)kN * kHid, 2);
  unsigned short* txtbf = (unsigned short*)alloc((size_t)kTxtRows * kEmbPad, 2);
  unsigned short* imgbf = (unsigned short*)alloc((size_t)kB * kI * 2048, 2);
  unsigned short* wtTx  = (unsigned short*)alloc((size_t)kHid * kEmbPad, 2);
  unsigned short* wtIm  = (unsigned short*)alloc((size_t)kHid * 2048, 2);
  unsigned short* wtG0  = (unsigned short*)alloc((size_t)kHid * kHid, 2);
  unsigned short* wtG1  = (unsigned short*)alloc((size_t)kHid * kHid, 2);
  unsigned short* wtG2  = (unsigned short*)alloc((size_t)kOut * kHid, 2);
  float* Cimg   = (float*)alloc((size_t)kB * kI * kHid, 4);
  float* Cg2    = (float*)alloc((size_t)kCap * kOut, 4);
  float* sentb  = (float*)alloc((size_t)kB * kS * kEmb, 4);
  float* uttb   = (float*)alloc((size_t)kB * kU * kEmb, 4);
  float* sessb  = (float*)alloc((size_t)kB * kEmb, 4);
  float* el     = (float*)alloc((size_t)kN * 4, 4);
  float* er     = (float*)alloc((size_t)kN * 4, 4);
  int*   offs   = (int*)alloc(kN + 1, 4);
  int*   cnt    = (int*)alloc(kN, 4);
  int*   csr    = (int*)alloc(E, 4);
  int*   rmt    = (int*)alloc(kTxtRows, 4);
  int*   rmi    = (int*)alloc(kB * kI, 4);
  int*   rowl   = (int*)alloc(kCap, 4);
  int*   info   = (int*)alloc(16, 4);
  (void)ws_size; (void)n_in; (void)out_size;

  // --- feature construction + prep ---
  k_sent<<<kB * kS, 128, 0, stream>>>(sentences, sent_mask, word_embed, sentb);
  k_utt<<<kB * kU, 128, 0, stream>>>(utterances, utt_mask, sentb, uttb);
  k_sess<<<kB, 128, 0, stream>>>(uttb, sessb);
  k_txtgather<<<kTxtRows, 128, 0, stream>>>(all_words, word_embed, sentb, uttb, sessb, txtbf);
  k_rowmap<<<(kTxtRows + 255) / 256, 256, 0, stream>>>(rmt, rmi);
  k_prep<<<5440, dim3(32, 8), 0, stream>>>(text_fc_w, wtTx, image_fc_w, wtIm,
                                           gat0_fc, wtG0, gat1_fc, wtG1, gat2_fc, wtG2,
                                           image_feats, imgbf);

  // --- CSR build ---
  hipMemsetAsync(cnt, 0, kN * sizeof(int), stream);
  k_count<<<(E + 255) / 256, 256, 0, stream>>>(edge_dst, cnt, E);
  k_scan<<<1, 1024, 0, stream>>>(cnt, offs, kN);
  hipMemsetAsync(cnt, 0, kN * sizeof(int), stream);
  k_fill<<<(E + 255) / 256, 256, 0, stream>>>(edge_src, edge_dst, offs, cnt, csr, E);

  // --- text FC (MFMA, scatter bf16) ---
  k_mm2<true><<<dim3(kHid / 128, (kTxtRows + 127) / 128), 256, 0, stream>>>(
      txtbf, wtTx, text_fc_b, rmt, Abf, kTxtRows, kEmbPad, kHid);

  // --- image FC via split-K ---
  hipMemsetAsync(Cimg, 0, (size_t)kB * kI * kHid * sizeof(float), stream);
  k_mm_sk<<<dim3(kHid / 64, kB * kI / 64, 4), 256, 0, stream>>>(
      imgbf, wtIm, nullptr, Cimg, kB * kI, 2048, kHid, 512);
  k_sk_epi<<<(kB * kI * kHid + 255) / 256, 256, 0, stream>>>(
      Cimg, image_fc_b, rmi, Abf, kB * kI, kHid);

  // --- GAT layer 0 ---
  k_mm2<true><<<dim3(kHid / 128, (kN + 127) / 128), 256, 0, stream>>>(
      Abf, wtG0, nullptr, nullptr, fbf, kN, kHid, kHid);
  k_elr4<<<kN, 256, 0, stream>>>(fbf, gat0_al, gat0_ar, el, er);
  k_agg3<<<kN, 256, 0, stream>>>(fbf, el, er, offs, csr, gat0_b, Abf);

  // --- GAT layer 1 ---
  k_mm2<true><<<dim3(kHid / 128, (kN + 127) / 128), 256, 0, stream>>>(
      Abf, wtG1, nullptr, nullptr, fbf, kN, kHid, kHid);
  k_elr4<<<kN, 256, 0, stream>>>(fbf, gat1_al, gat1_ar, el, er);
  k_agg3<<<kN, 256, 0, stream>>>(fbf, el, er, offs, csr, gat1_b, Abf);

  // --- GAT layer 2, sparse ---
  k_rows2<<<1, 64, 0, stream>>>(session_ids, offs, csr, rowl, info);
  hipMemsetAsync(Cg2, 0, (size_t)kCap * kOut * sizeof(float), stream);
  k_mm_sk<<<dim3(kOut / 64, kCap / 64, 4), 256, 0, stream>>>(
      Abf, wtG2, rowl, Cg2, kCap, kHid, kOut, 256);
  k_elr_c<<<kCap, 64, 0, stream>>>(Cg2, gat2_al, gat2_ar, el, er);
  k_agg_fin2<<<kB, 256, 0, stream>>>(Cg2, el, er, info, gat2_b, (float*)d_out);
}

// Round 10
// 444.010 us; speedup vs baseline: 1.5370x; 1.0188x over previous
//
#include <hip/hip_runtime.h>
#include <math.h>

// ---------------- problem constants ----------------
constexpr int kB = 4, kW = 2000, kI = 64, kS = 64, kT = 24, kU = 32, kUS = 2;
constexpr int kPER = kW + kI + kS + kU + 1;   // 2161 nodes per graph
constexpr int kN   = kB * kPER;               // 8644 nodes total
constexpr int kTxtPer  = kW + kS + kU + 1;    // 2097 text rows per graph
constexpr int kTxtRows = kB * kTxtPer;        // 8388 text rows
constexpr int kEmb = 300;
constexpr int kEmbPad = 320;
constexpr int kHid = 1024;
constexpr int kOut = 512;
constexpr int kCap = 256;                     // max gathered rows for sparse gat2
constexpr int kMaxDeg = 256;                  // softmax LDS capacity per head

typedef __attribute__((ext_vector_type(8))) short bf16x8;
typedef __attribute__((ext_vector_type(4))) float f32x4;

__device__ __forceinline__ unsigned short f2bf(float f) {
  union { float f; unsigned int u; } x; x.f = f;
  unsigned int r = x.u + 0x7FFF + ((x.u >> 16) & 1);
  return (unsigned short)(r >> 16);
}
__device__ __forceinline__ float bf2f(unsigned short u) {
  union { unsigned int u; float f; } x; x.u = ((unsigned int)u) << 16;
  return x.f;
}

// ---------------- feature construction (fp32) ----------------

__global__ void k_sent(const int* __restrict__ sents, const float* __restrict__ smask,
                       const float* __restrict__ wemb, float* __restrict__ sent) {
  int bs = blockIdx.x;
  __shared__ int idx[kT];
  __shared__ float mk[kT];
  __shared__ float s_cnt;
  int t = threadIdx.x;
  if (t < kT) { idx[t] = sents[bs * kT + t]; mk[t] = smask[bs * kT + t]; }
  __syncthreads();
  if (t == 0) {
    float c = 0.f;
    for (int i = 0; i < kT; ++i) c += mk[i];
    s_cnt = (c == 0.f) ? 1.f : c;
  }
  __syncthreads();
  for (int d = t; d < kEmb; d += blockDim.x) {
    float acc = 0.f;
    for (int i = 0; i < kT; ++i) acc += wemb[idx[i] * kEmb + d] * mk[i];
    sent[bs * kEmb + d] = acc / s_cnt;
  }
}

__global__ void k_utt(const int* __restrict__ utts, const float* __restrict__ umask,
                      const float* __restrict__ sent, float* __restrict__ utt) {
  int bu = blockIdx.x;
  int b = bu / kU;
  __shared__ int idx[kUS];
  __shared__ float mk[kUS];
  __shared__ float s_cnt;
  int t = threadIdx.x;
  if (t < kUS) { idx[t] = utts[bu * kUS + t]; mk[t] = umask[bu * kUS + t]; }
  __syncthreads();
  if (t == 0) {
    float c = 0.f;
    for (int i = 0; i < kUS; ++i) c += mk[i];
    s_cnt = (c == 0.f) ? 1.f : c;
  }
  __syncthreads();
  for (int d = t; d < kEmb; d += blockDim.x) {
    float acc = 0.f;
    for (int i = 0; i < kUS; ++i) acc += sent[(b * kS + idx[i]) * kEmb + d] * mk[i];
    utt[bu * kEmb + d] = acc / s_cnt;
  }
}

__global__ void k_sess(const float* __restrict__ utt, float* __restrict__ sess) {
  int b = blockIdx.x;
  for (int d = threadIdx.x; d < kEmb; d += blockDim.x) {
    float acc = 0.f;
    for (int u = 0; u < kU; ++u) acc += utt[(b * kU + u) * kEmb + d];
    sess[b * kEmb + d] = acc * (1.f / kU);
  }
}

__global__ void k_txtgather(const int* __restrict__ aw, const float* __restrict__ wemb,
                            const float* __restrict__ sent, const float* __restrict__ utt,
                            const float* __restrict__ sess, unsigned short* __restrict__ txt) {
  int r = blockIdx.x;
  int g = r / kTxtPer, j = r - g * kTxtPer;
  const float* src;
  if (j < kW)                 src = wemb + (size_t)aw[g * kW + j] * kEmb;
  else if (j < kW + kS)       src = sent + (size_t)(g * kS + (j - kW)) * kEmb;
  else if (j < kW + kS + kU)  src = utt  + (size_t)(g * kU + (j - kW - kS)) * kEmb;
  else                        src = sess + (size_t)g * kEmb;
  for (int d = threadIdx.x; d < kEmbPad; d += blockDim.x)
    txt[(size_t)r * kEmbPad + d] = (d < kEmb) ? f2bf(src[d]) : (unsigned short)0;
}

__global__ void k_rowmap(int* __restrict__ rt, int* __restrict__ ri) {
  int i = blockIdx.x * blockDim.x + threadIdx.x;
  if (i < kTxtRows) {
    int g = i / kTxtPer, j = i - g * kTxtPer;
    int base = g * kPER;
    int node;
    if (j < kW)                 node = base + j;
    else if (j < kW + kS)       node = base + kW + kI + (j - kW);
    else if (j < kW + kS + kU)  node = base + kW + kI + kS + (j - kW - kS);
    else                        node = base + kW + kI + kS + kU;
    rt[i] = node;
  }
  if (i < kB * kI) {
    int g = i >> 6;
    ri[i] = g * kPER + kW + (i & 63);
  }
}

// ---------------- fused prep: 5 weight transposes + image f2bf ----------------
__global__ void k_prep(const float* __restrict__ tx_w, unsigned short* __restrict__ o_tx,
                       const float* __restrict__ im_w, unsigned short* __restrict__ o_im,
                       const float* __restrict__ g0_w, unsigned short* __restrict__ o_g0,
                       const float* __restrict__ g1_w, unsigned short* __restrict__ o_g1,
                       const float* __restrict__ g2_w, unsigned short* __restrict__ o_g2,
                       const float* __restrict__ img, unsigned short* __restrict__ o_img) {
  int b = blockIdx.x;
  int tx = threadIdx.x, ty = threadIdx.y;
  const float* in; unsigned short* out; int K, N, Kpad, nbx;
  if (b < 320)               { in = tx_w; out = o_tx; K = kEmb; N = kHid; Kpad = kEmbPad; nbx = 32; }
  else if ((b -= 320) < 2048){ in = im_w; out = o_im; K = 2048; N = kHid; Kpad = 2048; nbx = 32; }
  else if ((b -= 2048) < 1024){ in = g0_w; out = o_g0; K = kHid; N = kHid; Kpad = kHid; nbx = 32; }
  else if ((b -= 1024) < 1024){ in = g1_w; out = o_g1; K = kHid; N = kHid; Kpad = kHid; nbx = 32; }
  else if ((b -= 1024) < 512) { in = g2_w; out = o_g2; K = kHid; N = kOut; Kpad = kHid; nbx = 16; }
  else {
    int i = (b - 512) * 1024 + (ty * 32 + tx) * 4;
    float4 v = *(const float4*)(img + i);
    ushort4 o; o.x = f2bf(v.x); o.y = f2bf(v.y); o.z = f2bf(v.z); o.w = f2bf(v.w);
    *(ushort4*)(o_img + i) = o;
    return;
  }
  int bx = b % nbx, by = b / nbx;
  __shared__ float t[32][33];
  int n = bx * 32 + tx;
#pragma unroll
  for (int j = 0; j < 4; ++j) {
    int k = by * 32 + ty + j * 8;
    t[ty + j * 8][tx] = (k < K) ? in[(size_t)k * N + n] : 0.f;
  }
  __syncthreads();
#pragma unroll
  for (int j = 0; j < 4; ++j) {
    int nn = bx * 32 + ty + j * 8;
    int kk = by * 32 + tx;
    out[(size_t)nn * Kpad + kk] = f2bf(t[tx][ty + j * 8]);
  }
}

// ---------------- bf16 MFMA GEMM, XCD-banded 1-D grid ----------------
// 128x128 tile, 4 waves, XOR-swizzled LDS (chunk c of row r at c^(r&7)).
// Grid is 1-D: i -> xcd = i&7, j = i>>3; colTile = j % nCol, rowTile = (j/nCol)*8 + xcd.
// With round-robin workgroup->XCD dispatch, each XCD owns a band of row-tiles:
// A-band (~2.3 MB) + full B (2 MB) stay L2-resident -> A fetched once overall.
template <bool OBF>
__global__ __launch_bounds__(256) void k_mm2(const unsigned short* __restrict__ A,
                                             const unsigned short* __restrict__ Bt,
                                             const float* __restrict__ bias,
                                             const int* __restrict__ rmap,
                                             void* __restrict__ Cout,
                                             int M, int K, int Nc) {
  __shared__ __align__(16) unsigned short As[128 * 64];
  __shared__ __align__(16) unsigned short Bs[128 * 64];
  int nCol = Nc >> 7;
  int bi = blockIdx.x;
  int xcd = bi & 7, bj = bi >> 3;
  int colTile = bj % nCol;
  int rowTile = ((bj / nCol) << 3) + xcd;
  int row0 = rowTile << 7;
  if (row0 >= M) return;                 // uniform early-exit (pre-barrier)
  int col0 = colTile << 7;

  int tid = threadIdx.x;
  int wid = tid >> 6, lane = tid & 63, quad = lane >> 4, l16 = lane & 15;
  int wm = wid >> 1, wn = wid & 1;

  f32x4 acc[4][4];
  f32x4 zero4 = {0.f, 0.f, 0.f, 0.f};
#pragma unroll
  for (int i = 0; i < 4; ++i)
#pragma unroll
    for (int j = 0; j < 4; ++j) acc[i][j] = zero4;

  int ar_ = tid >> 3;       // 0..31: row within 32-row slab
  int ac = tid & 7;         // 16B chunk index 0..7

  for (int k0 = 0; k0 < K; k0 += 64) {
    __syncthreads();
#pragma unroll
    for (int i = 0; i < 4; ++i) {
      int r = ar_ + i * 32;
      int sw = ((ac ^ (r & 7)) << 3);
      int grow = row0 + r;
      uint4 va = make_uint4(0u, 0u, 0u, 0u);
      if (grow < M) va = *(const uint4*)(A + (size_t)grow * K + k0 + ac * 8);
      *(uint4*)&As[r * 64 + sw] = va;
      int nrow = col0 + r;
      uint4 vb = *(const uint4*)(Bt + (size_t)nrow * K + k0 + ac * 8);
      *(uint4*)&Bs[r * 64 + sw] = vb;
    }
    __syncthreads();
#pragma unroll
    for (int s = 0; s < 2; ++s) {
      int cc = s * 4 + quad;
      bf16x8 aF[4], bF[4];
#pragma unroll
      for (int mi = 0; mi < 4; ++mi) {
        int r = wm * 64 + mi * 16 + l16;
        aF[mi] = *(const bf16x8*)&As[r * 64 + ((cc ^ (r & 7)) << 3)];
      }
#pragma unroll
      for (int ni = 0; ni < 4; ++ni) {
        int r = wn * 64 + ni * 16 + l16;
        bF[ni] = *(const bf16x8*)&Bs[r * 64 + ((cc ^ (r & 7)) << 3)];
      }
#pragma unroll
      for (int mi = 0; mi < 4; ++mi)
#pragma unroll
        for (int ni = 0; ni < 4; ++ni)
          acc[mi][ni] = __builtin_amdgcn_mfma_f32_16x16x32_bf16(aF[mi], bF[ni], acc[mi][ni], 0, 0, 0);
    }
  }

  // ---- epilogue: store (C/D layout: col=lane&15, row=quad*4+reg) ----
#pragma unroll
  for (int mi = 0; mi < 4; ++mi) {
#pragma unroll
    for (int ni = 0; ni < 4; ++ni) {
      int gm0 = row0 + wm * 64 + mi * 16 + quad * 4;
      int gn  = col0 + wn * 64 + ni * 16 + l16;
      float bv = bias ? bias[gn] : 0.f;
#pragma unroll
      for (int i = 0; i < 4; ++i) {
        int r = gm0 + i;
        if (r >= M) continue;
        float v = acc[mi][ni][i] + bv;
        if (OBF) {
          int orow = rmap ? rmap[r] : r;
          ((unsigned short*)Cout)[(size_t)orow * Nc + gn] = f2bf(v);
        } else {
          ((float*)Cout)[(size_t)r * Nc + gn] = v;
        }
      }
    }
  }
}

// ---------------- attention logits, bf16 f, H=4 D=256 ----------------
__global__ void k_elr4(const unsigned short* __restrict__ f, const float* __restrict__ al,
                       const float* __restrict__ ar, float* __restrict__ el,
                       float* __restrict__ er) {
  int v = blockIdx.x;
  int h = threadIdx.x >> 6, lane = threadIdx.x & 63;
  int d = lane * 4;
  ushort4 fv = *(const ushort4*)(f + (size_t)v * 1024 + h * 256 + d);
  float4 av = *(const float4*)(al + h * 256 + d);
  float4 rv = *(const float4*)(ar + h * 256 + d);
  float x0 = bf2f(fv.x), x1 = bf2f(fv.y), x2 = bf2f(fv.z), x3 = bf2f(fv.w);
  float a = x0 * av.x + x1 * av.y + x2 * av.z + x3 * av.w;
  float b = x0 * rv.x + x1 * rv.y + x2 * rv.z + x3 * rv.w;
#pragma unroll
  for (int off = 32; off; off >>= 1) {
    a += __shfl_down(a, off);
    b += __shfl_down(b, off);
  }
  if (lane == 0) { el[v * 4 + h] = a; er[v * 4 + h] = b; }
}

// ---------------- split-K bf16 MFMA GEMM (64x64 tile, optional A-row gather) ----------------
__global__ __launch_bounds__(256) void k_mm_sk(const unsigned short* __restrict__ A,
                                               const unsigned short* __restrict__ Bt,
                                               const int* __restrict__ rowlist,
                                               float* __restrict__ C,
                                               int M, int K, int Nc, int Kc) {
  __shared__ __align__(16) unsigned short As[64 * 64];
  __shared__ __align__(16) unsigned short Bs[64 * 64];
  int tid = threadIdx.x;
  int wid = tid >> 6, lane = tid & 63, quad = lane >> 4, l16 = lane & 15;
  int row0 = blockIdx.y * 64, col0 = blockIdx.x * 64;
  int k0 = blockIdx.z * Kc;
  int k1 = k0 + Kc; if (k1 > K) k1 = K;

  f32x4 acc[4];
  f32x4 zero4 = {0.f, 0.f, 0.f, 0.f};
#pragma unroll
  for (int i = 0; i < 4; ++i) acc[i] = zero4;

  int ar_ = tid >> 3;
  int ac = tid & 7;

  for (int kk = k0; kk < k1; kk += 64) {
    __syncthreads();
#pragma unroll
    for (int i = 0; i < 2; ++i) {
      int r = ar_ + i * 32;
      int sw = ((ac ^ (r & 7)) << 3);
      int grow = row0 + r;
      uint4 va = make_uint4(0u, 0u, 0u, 0u);
      if (grow < M) {
        int arow = rowlist ? rowlist[grow] : grow;
        va = *(const uint4*)(A + (size_t)arow * K + kk + ac * 8);
      }
      *(uint4*)&As[r * 64 + sw] = va;
      int nrow = col0 + r;
      uint4 vb = *(const uint4*)(Bt + (size_t)nrow * K + kk + ac * 8);
      *(uint4*)&Bs[r * 64 + sw] = vb;
    }
    __syncthreads();
#pragma unroll
    for (int s = 0; s < 2; ++s) {
      int cc = s * 4 + quad;
      bf16x8 bF;
      {
        int r = wid * 16 + l16;
        bF = *(const bf16x8*)&Bs[r * 64 + ((cc ^ (r & 7)) << 3)];
      }
#pragma unroll
      for (int mi = 0; mi < 4; ++mi) {
        int r = mi * 16 + l16;
        bf16x8 aF = *(const bf16x8*)&As[r * 64 + ((cc ^ (r & 7)) << 3)];
        acc[mi] = __builtin_amdgcn_mfma_f32_16x16x32_bf16(aF, bF, acc[mi], 0, 0, 0);
      }
    }
  }
#pragma unroll
  for (int mi = 0; mi < 4; ++mi) {
#pragma unroll
    for (int i = 0; i < 4; ++i) {
      int r = row0 + mi * 16 + quad * 4 + i;
      int c = col0 + wid * 16 + l16;
      if (r < M) atomicAdd(&C[(size_t)r * Nc + c], acc[mi][i]);
    }
  }
}

__global__ void k_sk_epi(const float* __restrict__ Cw, const float* __restrict__ bias,
                         const int* __restrict__ rmap, unsigned short* __restrict__ out,
                         int M, int Nc) {
  int i = blockIdx.x * blockDim.x + threadIdx.x;
  if (i >= M * Nc) return;
  int r = i / Nc, c = i - r * Nc;
  out[(size_t)rmap[r] * Nc + c] = f2bf(Cw[i] + bias[c]);
}

// ---------------- CSR build ----------------
__global__ void k_count(const int* __restrict__ dst, int* __restrict__ cnt, int E) {
  int e = blockIdx.x * blockDim.x + threadIdx.x;
  if (e < E) atomicAdd(&cnt[dst[e]], 1);
}

__global__ void k_scan(const int* __restrict__ deg, int* __restrict__ offs, int n) {
  __shared__ int part[1024];
  int tid = threadIdx.x;
  int per = (n + 1023) >> 10;
  int start = tid * per;
  int local = 0;
  for (int i = 0; i < per; ++i) { int idx = start + i; if (idx < n) local += deg[idx]; }
  part[tid] = local;
  __syncthreads();
  for (int off = 1; off < 1024; off <<= 1) {
    int add = (tid >= off) ? part[tid - off] : 0;
    __syncthreads();
    part[tid] += add;
    __syncthreads();
  }
  int run = (tid == 0) ? 0 : part[tid - 1];
  for (int i = 0; i < per; ++i) {
    int idx = start + i;
    if (idx < n) { offs[idx] = run; run += deg[idx]; }
  }
  if (tid == 1023) offs[n] = part[1023];
}

__global__ void k_fill(const int* __restrict__ src, const int* __restrict__ dst,
                       const int* __restrict__ offs, int* __restrict__ cur,
                       int* __restrict__ csr, int E) {
  int e = blockIdx.x * blockDim.x + threadIdx.x;
  if (e < E) {
    int d = dst[e];
    int slot = offs[d] + atomicAdd(&cur[d], 1);
    csr[slot] = src[e];
  }
}

// ---------------- fused softmax + aggregation (H=4, D=256, ELU, bf16 in/out) ----------------
__global__ __launch_bounds__(256) void k_agg3(const unsigned short* __restrict__ f,
                                              const float* __restrict__ el,
                                              const float* __restrict__ er,
                                              const int* __restrict__ offs,
                                              const int* __restrict__ csr,
                                              const float* __restrict__ bias,
                                              unsigned short* __restrict__ out) {
  __shared__ float xs[4][kMaxDeg];
  int v = blockIdx.x;
  int tid = threadIdx.x;
  int h = tid >> 6, lane = tid & 63;
  int e0 = offs[v];
  int deg = offs[v + 1] - e0;
  if (deg > kMaxDeg) deg = kMaxDeg;

  // ---- stage 1 (per-wave, lane-parallel over edges): softmax weights -> LDS ----
  float erv = er[v * 4 + h];
  float m = -1e30f;
  for (int base = 0; base < deg; base += 64) {
    int idx = base + lane;
    float x = -1e30f;
    if (idx < deg) {
      int s = csr[e0 + idx];
      x = el[s * 4 + h] + erv;
      x = x > 0.f ? x : 0.2f * x;
      xs[h][idx] = x;
    }
    float mm = x;
#pragma unroll
    for (int o = 32; o; o >>= 1) mm = fmaxf(mm, __shfl_xor(mm, o));
    m = fmaxf(m, mm);
  }
  float zs = 0.f;
  for (int base = 0; base < deg; base += 64) {
    int idx = base + lane;
    if (idx < deg) {
      float w = expf(xs[h][idx] - m);
      xs[h][idx] = w;
      zs += w;
    }
  }
#pragma unroll
  for (int o = 32; o; o >>= 1) zs += __shfl_xor(zs, o);
  float rz = 1.f / zs;
  for (int base = 0; base < deg; base += 64) {
    int idx = base + lane;
    if (idx < deg) xs[h][idx] *= rz;
  }
  __syncthreads();

  // ---- stage 2 (all threads): weighted gather ----
  int d0 = tid * 4;
  float a0 = 0.f, a1 = 0.f, a2 = 0.f, a3 = 0.f;
  for (int e = 0; e < deg; ++e) {
    int s = csr[e0 + e];
    float w = xs[h][e];
    ushort4 fv = *(const ushort4*)(f + (size_t)s * 1024 + d0);
    a0 += w * bf2f(fv.x);
    a1 += w * bf2f(fv.y);
    a2 += w * bf2f(fv.z);
    a3 += w * bf2f(fv.w);
  }
  float4 bv = *(const float4*)(bias + d0);
  float o0 = a0 + bv.x, o1 = a1 + bv.y, o2 = a2 + bv.z, o3 = a3 + bv.w;
  o0 = o0 > 0.f ? o0 : expm1f(o0);
  o1 = o1 > 0.f ? o1 : expm1f(o1);
  o2 = o2 > 0.f ? o2 : expm1f(o2);
  o3 = o3 > 0.f ? o3 : expm1f(o3);
  ushort4 ov;
  ov.x = f2bf(o0); ov.y = f2bf(o1); ov.z = f2bf(o2); ov.w = f2bf(o3);
  *(ushort4*)(out + (size_t)v * 1024 + d0) = ov;
}

// ---------------- sparse gat2 helpers ----------------
// Parallel rowlist build: wave bv handles session node bv; lanes copy edges.
__global__ void k_rows2(const int* __restrict__ sid, const int* __restrict__ offs,
                        const int* __restrict__ csr, int* __restrict__ rowlist,
                        int* __restrict__ info) {
  __shared__ int degs[kB], starts[kB], total;
  int tid = threadIdx.x;
  int bv = tid >> 6, lane = tid & 63;
  if (tid < kB) {
    int v = sid[tid];
    degs[tid] = offs[v + 1] - offs[v];
  }
  __syncthreads();
  if (tid == 0) {
    int p = 0;
    for (int b = 0; b < kB; ++b) {
      starts[b] = p;
      int d = degs[b];
      if (p + d > kCap) d = kCap - p;
      degs[b] = d;
      p += d;
    }
    total = p;
  }
  __syncthreads();
  int v = sid[bv];
  int e0 = offs[v];
  int deg = degs[bv];
  int start = starts[bv];
  if (lane == 0) {
    info[bv] = start;
    info[4 + bv] = deg;
    info[8 + bv] = start;   // fallback; overwritten below when self-loop found
  }
  __syncthreads();
  for (int idx = lane; idx < deg; idx += 64) {
    int s = csr[e0 + idx];
    rowlist[start + idx] = s;
    if (s == v) info[8 + bv] = start + idx;
  }
  // zero-pad the tail so the gat2 GEMM reads valid rows
  for (int i = total + tid; i < kCap; i += 256) rowlist[i] = 0;
}

__global__ void k_elr_c(const float* __restrict__ fc, const float* __restrict__ al,
                        const float* __restrict__ ar, float* __restrict__ el,
                        float* __restrict__ er) {
  int r = blockIdx.x;
  int lane = threadIdx.x;
  float a = 0.f, b = 0.f;
  for (int d = lane * 4; d < 512; d += 256) {
    float4 x = *(const float4*)(fc + (size_t)r * 512 + d);
    float4 av = *(const float4*)(al + d);
    float4 rv = *(const float4*)(ar + d);
    a += x.x * av.x + x.y * av.y + x.z * av.z + x.w * av.w;
    b += x.x * rv.x + x.y * rv.y + x.z * rv.z + x.w * rv.w;
  }
#pragma unroll
  for (int off = 32; off; off >>= 1) {
    a += __shfl_down(a, off);
    b += __shfl_down(b, off);
  }
  if (lane == 0) { el[r] = a; er[r] = b; }
}

__global__ __launch_bounds__(256) void k_agg_fin2(const float* __restrict__ fc,
                                                  const float* __restrict__ el,
                                                  const float* __restrict__ er,
                                                  const int* __restrict__ info,
                                                  const float* __restrict__ bias,
                                                  float* __restrict__ out) {
  int bv = blockIdx.x;
  int tid = threadIdx.x;
  int start = info[bv], cnt = info[4 + bv];
  float erv = er[info[8 + bv]];
  float m = -1e30f;
  for (int i = 0; i < cnt; ++i) {
    float x = el[start + i] + erv;
    x = x > 0.f ? x : 0.2f * x;
    m = fmaxf(m, x);
  }
  float z = 0.f, a0 = 0.f, a1 = 0.f;
  for (int i = 0; i < cnt; ++i) {
    int r = start + i;
    float x = el[r] + erv;
    x = x > 0.f ? x : 0.2f * x;
    float w = expf(x - m);
    z += w;
    a0 += w * fc[(size_t)r * 512 + tid];
    a1 += w * fc[(size_t)r * 512 + 256 + tid];
  }
  out[bv * 512 + tid] = a0 / z + bias[tid];
  out[bv * 512 + 256 + tid] = a1 / z + bias[256 + tid];
}

// ---------------- launcher ----------------
extern "C" void kernel_launch(void* const* d_in, const int* in_sizes, int n_in,
                              void* d_out, int out_size, void* d_ws, size_t ws_size,
                              hipStream_t stream) {
  const int*   all_words   = (const int*)d_in[0];
  const float* image_feats = (const float*)d_in[1];
  const int*   sentences   = (const int*)d_in[2];
  const float* sent_mask   = (const float*)d_in[3];
  const int*   utterances  = (const int*)d_in[4];
  const float* utt_mask    = (const float*)d_in[5];
  const int*   session_ids = (const int*)d_in[6];
  const int*   edge_src    = (const int*)d_in[7];
  const int*   edge_dst    = (const int*)d_in[8];
  const float* word_embed  = (const float*)d_in[9];
  const float* text_fc_w   = (const float*)d_in[10];
  const float* text_fc_b   = (const float*)d_in[11];
  const float* image_fc_w  = (const float*)d_in[12];
  const float* image_fc_b  = (const float*)d_in[13];
  const float* gat0_fc     = (const float*)d_in[14];
  const float* gat0_al     = (const float*)d_in[15];
  const float* gat0_ar     = (const float*)d_in[16];
  const float* gat0_b      = (const float*)d_in[17];
  const float* gat1_fc     = (const float*)d_in[18];
  const float* gat1_al     = (const float*)d_in[19];
  const float* gat1_ar     = (const float*)d_in[20];
  const float* gat1_b      = (const float*)d_in[21];
  const float* gat2_fc     = (const float*)d_in[22];
  const float* gat2_al     = (const float*)d_in[23];
  const float* gat2_ar     = (const float*)d_in[24];
  const float* gat2_b      = (const float*)d_in[25];

  const int E = in_sizes[7];

  char* base = (char*)d_ws;
  size_t off = 0;
  auto alloc = [&](size_t elems, size_t esz) -> void* {
    void* p = base + off;
    off += ((elems * esz + 255) / 256) * 256;
    return p;
  };
  unsigned short* Abf   = (unsigned short*)alloc((size_t)kN * kHid, 2);
  unsigned short* fbf   = (unsigned short*)alloc((size_t)kN * kHid, 2);
  unsigned short* txtbf = (unsigned short*)alloc((size_t)kTxtRows * kEmbPad, 2);
  unsigned short* imgbf = (unsigned short*)alloc((size_t)kB * kI * 2048, 2);
  unsigned short* wtTx  = (unsigned short*)alloc((size_t)kHid * kEmbPad, 2);
  unsigned short* wtIm  = (unsigned short*)alloc((size_t)kHid * 2048, 2);
  unsigned short* wtG0  = (unsigned short*)alloc((size_t)kHid * kHid, 2);
  unsigned short* wtG1  = (unsigned short*)alloc((size_t)kHid * kHid, 2);
  unsigned short* wtG2  = (unsigned short*)alloc((size_t)kOut * kHid, 2);
  float* Cimg   = (float*)alloc((size_t)kB * kI * kHid, 4);
  float* Cg2    = (float*)alloc((size_t)kCap * kOut, 4);
  float* sentb  = (float*)alloc((size_t)kB * kS * kEmb, 4);
  float* uttb   = (float*)alloc((size_t)kB * kU * kEmb, 4);
  float* sessb  = (float*)alloc((size_t)kB * kEmb, 4);
  float* el     = (float*)alloc((size_t)kN * 4, 4);
  float* er     = (float*)alloc((size_t)kN * 4, 4);
  int*   offs   = (int*)alloc(kN + 1, 4);
  int*   cnt    = (int*)alloc(kN, 4);
  int*   csr    = (int*)alloc(E, 4);
  int*   rmt    = (int*)alloc(kTxtRows, 4);
  int*   rmi    = (int*)alloc(kB * kI, 4);
  int*   rowl   = (int*)alloc(kCap, 4);
  int*   info   = (int*)alloc(16, 4);
  (void)ws_size; (void)n_in; (void)out_size;

  // --- feature construction + prep ---
  k_sent<<<kB * kS, 128, 0, stream>>>(sentences, sent_mask, word_embed, sentb);
  k_utt<<<kB * kU, 128, 0, stream>>>(utterances, utt_mask, sentb, uttb);
  k_sess<<<kB, 128, 0, stream>>>(uttb, sessb);
  k_txtgather<<<kTxtRows, 128, 0, stream>>>(all_words, word_embed, sentb, uttb, sessb, txtbf);
  k_rowmap<<<(kTxtRows + 255) / 256, 256, 0, stream>>>(rmt, rmi);
  k_prep<<<5440, dim3(32, 8), 0, stream>>>(text_fc_w, wtTx, image_fc_w, wtIm,
                                           gat0_fc, wtG0, gat1_fc, wtG1, gat2_fc, wtG2,
                                           image_feats, imgbf);

  // --- CSR build ---
  hipMemsetAsync(cnt, 0, kN * sizeof(int), stream);
  k_count<<<(E + 255) / 256, 256, 0, stream>>>(edge_dst, cnt, E);
  k_scan<<<1, 1024, 0, stream>>>(cnt, offs, kN);
  hipMemsetAsync(cnt, 0, kN * sizeof(int), stream);
  k_fill<<<(E + 255) / 256, 256, 0, stream>>>(edge_src, edge_dst, offs, cnt, csr, E);

  // XCD-banded 1-D grids: 8 * nCol * ceil(nRowTiles/8)
  auto mmGrid = [](int M, int Nc) {
    int nrt = (M + 127) / 128;
    return 8 * (Nc / 128) * ((nrt + 7) / 8);
  };

  // --- text FC (MFMA, scatter bf16) ---
  k_mm2<true><<<mmGrid(kTxtRows, kHid), 256, 0, stream>>>(
      txtbf, wtTx, text_fc_b, rmt, Abf, kTxtRows, kEmbPad, kHid);

  // --- image FC via split-K ---
  hipMemsetAsync(Cimg, 0, (size_t)kB * kI * kHid * sizeof(float), stream);
  k_mm_sk<<<dim3(kHid / 64, kB * kI / 64, 4), 256, 0, stream>>>(
      imgbf, wtIm, nullptr, Cimg, kB * kI, 2048, kHid, 512);
  k_sk_epi<<<(kB * kI * kHid + 255) / 256, 256, 0, stream>>>(
      Cimg, image_fc_b, rmi, Abf, kB * kI, kHid);

  // --- GAT layer 0 ---
  k_mm2<true><<<mmGrid(kN, kHid), 256, 0, stream>>>(
      Abf, wtG0, nullptr, nullptr, fbf, kN, kHid, kHid);
  k_elr4<<<kN, 256, 0, stream>>>(fbf, gat0_al, gat0_ar, el, er);
  k_agg3<<<kN, 256, 0, stream>>>(fbf, el, er, offs, csr, gat0_b, Abf);

  // --- GAT layer 1 ---
  k_mm2<true><<<mmGrid(kN, kHid), 256, 0, stream>>>(
      Abf, wtG1, nullptr, nullptr, fbf, kN, kHid, kHid);
  k_elr4<<<kN, 256, 0, stream>>>(fbf, gat1_al, gat1_ar, el, er);
  k_agg3<<<kN, 256, 0, stream>>>(fbf, el, er, offs, csr, gat1_b, Abf);

  // --- GAT layer 2, sparse ---
  k_rows2<<<1, 256, 0, stream>>>(session_ids, offs, csr, rowl, info);
  hipMemsetAsync(Cg2, 0, (size_t)kCap * kOut * sizeof(float), stream);
  k_mm_sk<<<dim3(kOut / 64, kCap / 64, 4), 256, 0, stream>>>(
      Abf, wtG2, rowl, Cg2, kCap, kHid, kOut, 256);
  k_elr_c<<<kCap, 64, 0, stream>>>(Cg2, gat2_al, gat2_ar, el, er);
  k_agg_fin2<<<kB, 256, 0, stream>>>(Cg2, el, er, info, gat2_b, (float*)d_out);
}